// Round 2
// baseline (903.181 us; speedup 1.0000x reference)
//
#include <hip/hip_runtime.h>

#define F 128
#define BM 64

// ---------------- GEMM: h = x @ W  (f32, vector ALU) ----------------
// block = 256 threads, BM=64 rows/block. Each thread: 4 rows x 8 cols.
__global__ __launch_bounds__(256) void k_gemm(const float* __restrict__ x,
                                              const float* __restrict__ W,
                                              float* __restrict__ h, int N) {
  __shared__ float Xs[BM][F + 4];   // pad 4 floats: float4-aligned rows, 2-way LDS alias (free)
  __shared__ float Ws[32][F + 4];
  const int t = threadIdx.x;
  const int row0 = blockIdx.x * BM;

  // stage Xs: 8 passes, thread t -> row p*8 + (t>>5), float4 col (t&31)
  {
    const int r = t >> 5;
    const int c4 = t & 31;
#pragma unroll
    for (int p = 0; p < 8; ++p) {
      const int rr = p * 8 + r;
      const int grow = row0 + rr;
      float4 v = make_float4(0.f, 0.f, 0.f, 0.f);
      if (grow < N) v = *reinterpret_cast<const float4*>(&x[(size_t)grow * F + c4 * 4]);
      *reinterpret_cast<float4*>(&Xs[rr][c4 * 4]) = v;
    }
  }

  float acc[4][8];
#pragma unroll
  for (int i = 0; i < 4; ++i)
#pragma unroll
    for (int j = 0; j < 8; ++j) acc[i][j] = 0.f;

  const int cg = (t & 15) * 8;   // col base (8 cols)
  const int rg = (t >> 4) * 4;   // row base (4 rows)

  for (int k0 = 0; k0 < F; k0 += 32) {
    __syncthreads();   // protect Ws from previous iteration (also makes Xs visible at k0=0)
    {
      const int r = t >> 5;
      const int c4 = t & 31;
#pragma unroll
      for (int p = 0; p < 4; ++p) {
        const int kk = p * 8 + r;
        float4 v = *reinterpret_cast<const float4*>(&W[(size_t)(k0 + kk) * F + c4 * 4]);
        *reinterpret_cast<float4*>(&Ws[kk][c4 * 4]) = v;
      }
    }
    __syncthreads();
#pragma unroll
    for (int kk = 0; kk < 32; ++kk) {
      float xv[4];
#pragma unroll
      for (int i = 0; i < 4; ++i) xv[i] = Xs[rg + i][k0 + kk];
      const float4 w0 = *reinterpret_cast<const float4*>(&Ws[kk][cg]);
      const float4 w1 = *reinterpret_cast<const float4*>(&Ws[kk][cg + 4]);
      const float wv[8] = {w0.x, w0.y, w0.z, w0.w, w1.x, w1.y, w1.z, w1.w};
#pragma unroll
      for (int i = 0; i < 4; ++i)
#pragma unroll
        for (int j = 0; j < 8; ++j) acc[i][j] = fmaf(xv[i], wv[j], acc[i][j]);
    }
  }

#pragma unroll
  for (int i = 0; i < 4; ++i) {
    const int grow = row0 + rg + i;
    if (grow < N) {
      float4 o0 = make_float4(acc[i][0], acc[i][1], acc[i][2], acc[i][3]);
      float4 o1 = make_float4(acc[i][4], acc[i][5], acc[i][6], acc[i][7]);
      *reinterpret_cast<float4*>(&h[(size_t)grow * F + cg]) = o0;
      *reinterpret_cast<float4*>(&h[(size_t)grow * F + cg + 4]) = o1;
    }
  }
}

// ---------------- degree count (in-degree at dst; self-loop added later) ----------------
__global__ void k_deg(const int* __restrict__ dst, unsigned* __restrict__ deg, int E) {
  const int i = blockIdx.x * blockDim.x + threadIdx.x;
  if (i < E) atomicAdd(&deg[dst[i]], 1u);
}

__global__ void k_dinv(const unsigned* __restrict__ deg, float* __restrict__ dinv, int N) {
  const int i = blockIdx.x * blockDim.x + threadIdx.x;
  if (i < N) dinv[i] = rsqrtf((float)deg[i] + 1.0f);   // +1 = self loop; deg>0 always
}

// ---------------- edge scatter: out[dst] += dinv[src]*dinv[dst]*h[src] ----------------
// one wave per edge: lane l handles floats l and l+64 -> each atomic instr is a
// contiguous 256B span of one out-row (max same-line coalescing).
__global__ __launch_bounds__(256) void k_scatter(const float* __restrict__ h,
                                                 const float* __restrict__ dinv,
                                                 const int* __restrict__ src,
                                                 const int* __restrict__ dst,
                                                 float* __restrict__ out, int E) {
  const int lane = threadIdx.x & 63;
  const int wid = (int)((blockIdx.x * blockDim.x + threadIdx.x) >> 6);
  const int nw = (int)((gridDim.x * blockDim.x) >> 6);
  for (int e = wid; e < E; e += nw) {
    const int s = src[e];
    const int d = dst[e];
    const float nrm = dinv[s] * dinv[d];
    const float* hp = h + (size_t)s * F;
    float* op = out + (size_t)d * F;
    const float v0 = hp[lane] * nrm;
    const float v1 = hp[lane + 64] * nrm;
    unsafeAtomicAdd(&op[lane], v0);        // global_atomic_add_f32, no return
    unsafeAtomicAdd(&op[lane + 64], v1);
  }
}

// ---------------- finalize: out = relu(out + dinv^2 * h + b) ----------------
__global__ void k_final(const float* __restrict__ h, const float* __restrict__ dinv,
                        const float* __restrict__ b, float* __restrict__ out, int N) {
  const int i4 = blockIdx.x * blockDim.x + threadIdx.x;  // float4 index
  const int total = N * (F / 4);
  if (i4 >= total) return;
  const int node = i4 >> 5;
  const int c4 = (i4 & 31) * 4;
  const float di = dinv[node];
  const float s = di * di;
  const size_t off = (size_t)node * F + c4;
  const float4 hv = *reinterpret_cast<const float4*>(&h[off]);
  const float4 ov = *reinterpret_cast<const float4*>(&out[off]);
  const float4 bv = *reinterpret_cast<const float4*>(&b[c4]);
  float4 r;
  r.x = fmaxf(fmaf(s, hv.x, ov.x) + bv.x, 0.f);
  r.y = fmaxf(fmaf(s, hv.y, ov.y) + bv.y, 0.f);
  r.z = fmaxf(fmaf(s, hv.z, ov.z) + bv.z, 0.f);
  r.w = fmaxf(fmaf(s, hv.w, ov.w) + bv.w, 0.f);
  *reinterpret_cast<float4*>(&out[off]) = r;
}

extern "C" void kernel_launch(void* const* d_in, const int* in_sizes, int n_in,
                              void* d_out, int out_size, void* d_ws, size_t ws_size,
                              hipStream_t stream) {
  const float* x  = (const float*)d_in[0];
  const int*   ei = (const int*)d_in[1];     // int64 in ref -> int32 on device per harness
  const float* W  = (const float*)d_in[2];
  const float* b  = (const float*)d_in[3];
  float* out = (float*)d_out;

  const int N = in_sizes[0] / F;             // 100000
  const int E = in_sizes[1] / 2;             // 1600000
  const int* srcA = ei;                      // edge_index[0]
  const int* dstA = ei + E;                  // edge_index[1]

  // workspace layout: h [N*F f32] | deg [N u32] | dinv [N f32]
  float*    h    = (float*)d_ws;
  unsigned* deg  = (unsigned*)((char*)d_ws + (size_t)N * F * sizeof(float));
  float*    dinv = (float*)(deg + N);

  hipMemsetAsync(out, 0, (size_t)out_size * sizeof(float), stream);
  hipMemsetAsync(deg, 0, (size_t)N * sizeof(unsigned), stream);

  k_deg<<<(E + 255) / 256, 256, 0, stream>>>(dstA, deg, E);
  k_dinv<<<(N + 255) / 256, 256, 0, stream>>>(deg, dinv, N);
  k_gemm<<<(N + BM - 1) / BM, 256, 0, stream>>>(x, W, h, N);
  k_scatter<<<2048, 256, 0, stream>>>(h, dinv, srcA, dstA, out, E);
  k_final<<<(N * (F / 4) + 255) / 256, 256, 0, stream>>>(h, dinv, b, out, N);
}

// Round 3
// 521.159 us; speedup vs baseline: 1.7330x; 1.7330x over previous
//
#include <hip/hip_runtime.h>

#define F 128
#define BM 64

// ---------------- GEMM: h = x @ W  (f32, vector ALU) ----------------
__global__ __launch_bounds__(256) void k_gemm(const float* __restrict__ x,
                                              const float* __restrict__ W,
                                              float* __restrict__ h, int N) {
  __shared__ float Xs[BM][F + 4];
  __shared__ float Ws[32][F + 4];
  const int t = threadIdx.x;
  const int row0 = blockIdx.x * BM;

  {
    const int r = t >> 5;
    const int c4 = t & 31;
#pragma unroll
    for (int p = 0; p < 8; ++p) {
      const int rr = p * 8 + r;
      const int grow = row0 + rr;
      float4 v = make_float4(0.f, 0.f, 0.f, 0.f);
      if (grow < N) v = *reinterpret_cast<const float4*>(&x[(size_t)grow * F + c4 * 4]);
      *reinterpret_cast<float4*>(&Xs[rr][c4 * 4]) = v;
    }
  }

  float acc[4][8];
#pragma unroll
  for (int i = 0; i < 4; ++i)
#pragma unroll
    for (int j = 0; j < 8; ++j) acc[i][j] = 0.f;

  const int cg = (t & 15) * 8;
  const int rg = (t >> 4) * 4;

  for (int k0 = 0; k0 < F; k0 += 32) {
    __syncthreads();
    {
      const int r = t >> 5;
      const int c4 = t & 31;
#pragma unroll
      for (int p = 0; p < 4; ++p) {
        const int kk = p * 8 + r;
        float4 v = *reinterpret_cast<const float4*>(&W[(size_t)(k0 + kk) * F + c4 * 4]);
        *reinterpret_cast<float4*>(&Ws[kk][c4 * 4]) = v;
      }
    }
    __syncthreads();
#pragma unroll
    for (int kk = 0; kk < 32; ++kk) {
      float xv[4];
#pragma unroll
      for (int i = 0; i < 4; ++i) xv[i] = Xs[rg + i][k0 + kk];
      const float4 w0 = *reinterpret_cast<const float4*>(&Ws[kk][cg]);
      const float4 w1 = *reinterpret_cast<const float4*>(&Ws[kk][cg + 4]);
      const float wv[8] = {w0.x, w0.y, w0.z, w0.w, w1.x, w1.y, w1.z, w1.w};
#pragma unroll
      for (int i = 0; i < 4; ++i)
#pragma unroll
        for (int j = 0; j < 8; ++j) acc[i][j] = fmaf(xv[i], wv[j], acc[i][j]);
    }
  }

#pragma unroll
  for (int i = 0; i < 4; ++i) {
    const int grow = row0 + rg + i;
    if (grow < N) {
      float4 o0 = make_float4(acc[i][0], acc[i][1], acc[i][2], acc[i][3]);
      float4 o1 = make_float4(acc[i][4], acc[i][5], acc[i][6], acc[i][7]);
      *reinterpret_cast<float4*>(&h[(size_t)grow * F + cg]) = o0;
      *reinterpret_cast<float4*>(&h[(size_t)grow * F + cg + 4]) = o1;
    }
  }
}

// ---------------- degree count ----------------
__global__ void k_deg(const int* __restrict__ dst, unsigned* __restrict__ deg, int E) {
  const int i = blockIdx.x * blockDim.x + threadIdx.x;
  if (i < E) atomicAdd(&deg[dst[i]], 1u);
}

__global__ void k_dinv(const unsigned* __restrict__ deg, float* __restrict__ dinv, int N) {
  const int i = blockIdx.x * blockDim.x + threadIdx.x;
  if (i < N) dinv[i] = rsqrtf((float)deg[i] + 1.0f);   // +1 = self loop
}

// ---------------- scan pass A: per-block (1024 elems) sums ----------------
__global__ __launch_bounds__(256) void k_scanA(const unsigned* __restrict__ degpad,
                                               unsigned* __restrict__ bsum) {
  __shared__ unsigned sd[256];
  const int t = threadIdx.x, b = blockIdx.x;
  const uint4 d = *reinterpret_cast<const uint4*>(&degpad[b * 1024 + t * 4]);
  sd[t] = d.x + d.y + d.z + d.w;
  __syncthreads();
  for (int off = 128; off > 0; off >>= 1) {
    if (t < off) sd[t] += sd[t + off];
    __syncthreads();
  }
  if (t == 0) bsum[b] = sd[0];
}

// ---------------- scan pass B: exclusive scan of block sums (in place) ----------------
__global__ __launch_bounds__(1024) void k_scanB(unsigned* __restrict__ bsum, int NB) {
  __shared__ unsigned sd[1024];
  const int t = threadIdx.x;
  const unsigned v = (t < NB) ? bsum[t] : 0u;
  sd[t] = v;
  __syncthreads();
  for (int off = 1; off < 1024; off <<= 1) {
    const unsigned u = (t >= off) ? sd[t - off] : 0u;
    __syncthreads();
    sd[t] += u;
    __syncthreads();
  }
  if (t < NB) bsum[t] = sd[t] - v;   // exclusive
}

// ---------------- scan pass C: rowptr + cursor (cursor aliases degpad, in-place) ----------
__global__ __launch_bounds__(256) void k_scanC(const unsigned* __restrict__ degpad,
                                               int* __restrict__ rowptr,
                                               int* __restrict__ cursor,
                                               const unsigned* __restrict__ bexcl,
                                               int N, int E) {
  __shared__ unsigned sd[256];
  const int t = threadIdx.x, b = blockIdx.x;
  const int i0 = b * 1024 + t * 4;
  const uint4 d = *reinterpret_cast<const uint4*>(&degpad[i0]);   // read BEFORE cursor overwrite
  const unsigned p1 = d.x, p2 = p1 + d.y, p3 = p2 + d.z, tt = p3 + d.w;
  sd[t] = tt;
  __syncthreads();
  for (int off = 1; off < 256; off <<= 1) {
    const unsigned u = (t >= off) ? sd[t - off] : 0u;
    __syncthreads();
    sd[t] += u;
    __syncthreads();
  }
  const unsigned base = bexcl[b] + (sd[t] - tt);
  const unsigned r[4] = {base, base + p1, base + p2, base + p3};
#pragma unroll
  for (int k = 0; k < 4; ++k) {
    const int i = i0 + k;
    if (i < N) { rowptr[i] = (int)r[k]; cursor[i] = (int)r[k]; }
  }
  if (b == 0 && t == 0) rowptr[N] = E;
}

// ---------------- bin fill: esrc sorted-by-dst via cursor atomics ----------------
__global__ void k_binfill(const int* __restrict__ src, const int* __restrict__ dst,
                          int* __restrict__ cursor, int* __restrict__ esrc, int E) {
  const int i = blockIdx.x * blockDim.x + threadIdx.x;
  if (i < E) {
    const int p = atomicAdd(&cursor[dst[i]], 1);
    esrc[p] = src[i];
  }
}

// ---------------- gather: one wave per node, atomic-free, fused epilogue ----------------
__global__ __launch_bounds__(256) void k_gather(const float* __restrict__ h,
                                                const float* __restrict__ dinv,
                                                const int* __restrict__ rowptr,
                                                const int* __restrict__ esrc,
                                                const float* __restrict__ bias,
                                                float* __restrict__ out, int N) {
  const int lane = threadIdx.x & 63;
  const int v = (int)((blockIdx.x * blockDim.x + threadIdx.x) >> 6);
  if (v >= N) return;
  const int c = lane * 2;
  const float dv = dinv[v];
  const float2 hv = *reinterpret_cast<const float2*>(&h[(size_t)v * F + c]);
  float a0 = dv * hv.x;            // self loop: dinv[v]*h[v]; final *dv below
  float a1 = dv * hv.y;
  const int beg = rowptr[v], end = rowptr[v + 1];
  for (int j = beg; j < end; ++j) {
    const int s = esrc[j];
    const float ds = dinv[s];
    const float2 hs = *reinterpret_cast<const float2*>(&h[(size_t)s * F + c]);
    a0 = fmaf(ds, hs.x, a0);
    a1 = fmaf(ds, hs.y, a1);
  }
  const float2 bv = *reinterpret_cast<const float2*>(&bias[c]);
  float2 r;
  r.x = fmaxf(fmaf(dv, a0, bv.x), 0.f);
  r.y = fmaxf(fmaf(dv, a1, bv.y), 0.f);
  *reinterpret_cast<float2*>(&out[(size_t)v * F + c]) = r;
}

// ---------------- fallback (atomic scatter) kernels ----------------
__global__ __launch_bounds__(256) void k_scatter(const float* __restrict__ h,
                                                 const float* __restrict__ dinv,
                                                 const int* __restrict__ src,
                                                 const int* __restrict__ dst,
                                                 float* __restrict__ out, int E) {
  const int lane = threadIdx.x & 63;
  const int wid = (int)((blockIdx.x * blockDim.x + threadIdx.x) >> 6);
  const int nw = (int)((gridDim.x * blockDim.x) >> 6);
  for (int e = wid; e < E; e += nw) {
    const int s = src[e];
    const int d = dst[e];
    const float nrm = dinv[s] * dinv[d];
    const float* hp = h + (size_t)s * F;
    float* op = out + (size_t)d * F;
    unsafeAtomicAdd(&op[lane], hp[lane] * nrm);
    unsafeAtomicAdd(&op[lane + 64], hp[lane + 64] * nrm);
  }
}

__global__ void k_final(const float* __restrict__ h, const float* __restrict__ dinv,
                        const float* __restrict__ b, float* __restrict__ out, int N) {
  const int i4 = blockIdx.x * blockDim.x + threadIdx.x;
  const int total = N * (F / 4);
  if (i4 >= total) return;
  const int node = i4 >> 5;
  const int c4 = (i4 & 31) * 4;
  const float di = dinv[node];
  const float s = di * di;
  const size_t off = (size_t)node * F + c4;
  const float4 hv = *reinterpret_cast<const float4*>(&h[off]);
  const float4 ov = *reinterpret_cast<const float4*>(&out[off]);
  const float4 bv = *reinterpret_cast<const float4*>(&b[c4]);
  float4 r;
  r.x = fmaxf(fmaf(s, hv.x, ov.x) + bv.x, 0.f);
  r.y = fmaxf(fmaf(s, hv.y, ov.y) + bv.y, 0.f);
  r.z = fmaxf(fmaf(s, hv.z, ov.z) + bv.z, 0.f);
  r.w = fmaxf(fmaf(s, hv.w, ov.w) + bv.w, 0.f);
  *reinterpret_cast<float4*>(&out[off]) = r;
}

extern "C" void kernel_launch(void* const* d_in, const int* in_sizes, int n_in,
                              void* d_out, int out_size, void* d_ws, size_t ws_size,
                              hipStream_t stream) {
  const float* x  = (const float*)d_in[0];
  const int*   ei = (const int*)d_in[1];
  const float* W  = (const float*)d_in[2];
  const float* b  = (const float*)d_in[3];
  float* out = (float*)d_out;

  const int N = in_sizes[0] / F;   // 100000
  const int E = in_sizes[1] / 2;   // 1600000
  const int* srcA = ei;
  const int* dstA = ei + E;

  const int NB = (N + 1023) / 1024;       // 98
  const int Npad = NB * 1024;

  auto aln = [](size_t v) { return (v + 255) & ~(size_t)255; };
  char* base = (char*)d_ws;
  size_t off = 0;
  float* h = (float*)(base + off);        off += aln((size_t)N * F * sizeof(float));
  int* esrc = (int*)(base + off);         off += aln((size_t)E * sizeof(int));
  float* dinv = (float*)(base + off);     off += aln((size_t)N * sizeof(float));
  int* rowptr = (int*)(base + off);       off += aln((size_t)(N + 1) * sizeof(int));
  unsigned* degpad = (unsigned*)(base + off); off += aln((size_t)Npad * sizeof(unsigned));
  unsigned* bsum = (unsigned*)(base + off);   off += aln(1024 * sizeof(unsigned));
  const size_t needed = off;

  if (ws_size >= needed) {
    // ---- CSR path ----
    int* cursor = (int*)degpad;   // aliased: scanC reads deg then writes cursor in place
    hipMemsetAsync(degpad, 0, (size_t)Npad * sizeof(unsigned), stream);
    k_deg<<<(E + 255) / 256, 256, 0, stream>>>(dstA, degpad, E);
    k_dinv<<<(N + 255) / 256, 256, 0, stream>>>(degpad, dinv, N);
    k_scanA<<<NB, 256, 0, stream>>>(degpad, bsum);
    k_scanB<<<1, 1024, 0, stream>>>(bsum, NB);
    k_scanC<<<NB, 256, 0, stream>>>(degpad, rowptr, cursor, bsum, N, E);
    k_binfill<<<(E + 255) / 256, 256, 0, stream>>>(srcA, dstA, cursor, esrc, E);
    k_gemm<<<(N + BM - 1) / BM, 256, 0, stream>>>(x, W, h, N);
    k_gather<<<(N * 64 + 255) / 256, 256, 0, stream>>>(h, dinv, rowptr, esrc, b, out, N);
  } else {
    // ---- fallback: atomic scatter (round-2 behavior) ----
    hipMemsetAsync(out, 0, (size_t)out_size * sizeof(float), stream);
    hipMemsetAsync(degpad, 0, (size_t)Npad * sizeof(unsigned), stream);
    k_deg<<<(E + 255) / 256, 256, 0, stream>>>(dstA, degpad, E);
    k_dinv<<<(N + 255) / 256, 256, 0, stream>>>(degpad, dinv, N);
    k_gemm<<<(N + BM - 1) / BM, 256, 0, stream>>>(x, W, h, N);
    k_scatter<<<2048, 256, 0, stream>>>(h, dinv, srcA, dstA, out, E);
    k_final<<<(N * (F / 4) + 255) / 256, 256, 0, stream>>>(h, dinv, b, out, N);
  }
}

// Round 4
// 464.814 us; speedup vs baseline: 1.9431x; 1.1212x over previous
//
#include <hip/hip_runtime.h>

#define F 128
#define BM 64

// round-to-nearest-even f32 -> bf16 bits
__device__ inline uint32_t bfbits(float f) {
  uint32_t x = __float_as_uint(f);
  return (x + 0x7fffu + ((x >> 16) & 1u)) >> 16;
}

// ---------------- GEMM: h' = dinv[row] * (x @ W), stored bf16 ----------------
__global__ __launch_bounds__(256) void k_gemm(const float* __restrict__ x,
                                              const float* __restrict__ W,
                                              const float* __restrict__ dinv,
                                              uint32_t* __restrict__ hB, int N) {
  __shared__ float Xs[BM][F + 4];
  __shared__ float Ws[32][F + 4];
  const int t = threadIdx.x;
  const int row0 = blockIdx.x * BM;

  {
    const int r = t >> 5;
    const int c4 = t & 31;
#pragma unroll
    for (int p = 0; p < 8; ++p) {
      const int rr = p * 8 + r;
      const int grow = row0 + rr;
      float4 v = make_float4(0.f, 0.f, 0.f, 0.f);
      if (grow < N) v = *reinterpret_cast<const float4*>(&x[(size_t)grow * F + c4 * 4]);
      *reinterpret_cast<float4*>(&Xs[rr][c4 * 4]) = v;
    }
  }

  float acc[4][8];
#pragma unroll
  for (int i = 0; i < 4; ++i)
#pragma unroll
    for (int j = 0; j < 8; ++j) acc[i][j] = 0.f;

  const int cg = (t & 15) * 8;   // col base (8 cols)
  const int rg = (t >> 4) * 4;   // row base (4 rows)

  for (int k0 = 0; k0 < F; k0 += 32) {
    __syncthreads();
    {
      const int r = t >> 5;
      const int c4 = t & 31;
#pragma unroll
      for (int p = 0; p < 4; ++p) {
        const int kk = p * 8 + r;
        float4 v = *reinterpret_cast<const float4*>(&W[(size_t)(k0 + kk) * F + c4 * 4]);
        *reinterpret_cast<float4*>(&Ws[kk][c4 * 4]) = v;
      }
    }
    __syncthreads();
#pragma unroll
    for (int kk = 0; kk < 32; ++kk) {
      float xv[4];
#pragma unroll
      for (int i = 0; i < 4; ++i) xv[i] = Xs[rg + i][k0 + kk];
      const float4 w0 = *reinterpret_cast<const float4*>(&Ws[kk][cg]);
      const float4 w1 = *reinterpret_cast<const float4*>(&Ws[kk][cg + 4]);
      const float wv[8] = {w0.x, w0.y, w0.z, w0.w, w1.x, w1.y, w1.z, w1.w};
#pragma unroll
      for (int i = 0; i < 4; ++i)
#pragma unroll
        for (int j = 0; j < 8; ++j) acc[i][j] = fmaf(xv[i], wv[j], acc[i][j]);
    }
  }

#pragma unroll
  for (int i = 0; i < 4; ++i) {
    const int grow = row0 + rg + i;
    if (grow < N) {
      const float dv = dinv[grow];
      uint32_t p0 = bfbits(acc[i][0] * dv) | (bfbits(acc[i][1] * dv) << 16);
      uint32_t p1 = bfbits(acc[i][2] * dv) | (bfbits(acc[i][3] * dv) << 16);
      uint32_t p2 = bfbits(acc[i][4] * dv) | (bfbits(acc[i][5] * dv) << 16);
      uint32_t p3 = bfbits(acc[i][6] * dv) | (bfbits(acc[i][7] * dv) << 16);
      uint4 st = make_uint4(p0, p1, p2, p3);
      *reinterpret_cast<uint4*>(&hB[(size_t)grow * (F / 2) + cg / 2]) = st;
    }
  }
}

// ---------------- degree count ----------------
__global__ void k_deg(const int* __restrict__ dst, unsigned* __restrict__ deg, int E) {
  const int i = blockIdx.x * blockDim.x + threadIdx.x;
  if (i < E) atomicAdd(&deg[dst[i]], 1u);
}

// ---------------- scan pass A: per-block (1024 elems) sums ----------------
__global__ __launch_bounds__(256) void k_scanA(const unsigned* __restrict__ degpad,
                                               unsigned* __restrict__ bsum) {
  __shared__ unsigned sd[256];
  const int t = threadIdx.x, b = blockIdx.x;
  const uint4 d = *reinterpret_cast<const uint4*>(&degpad[b * 1024 + t * 4]);
  sd[t] = d.x + d.y + d.z + d.w;
  __syncthreads();
  for (int off = 128; off > 0; off >>= 1) {
    if (t < off) sd[t] += sd[t + off];
    __syncthreads();
  }
  if (t == 0) bsum[b] = sd[0];
}

// ---------------- scan pass B: exclusive scan of block sums ----------------
__global__ __launch_bounds__(1024) void k_scanB(unsigned* __restrict__ bsum, int NB) {
  __shared__ unsigned sd[1024];
  const int t = threadIdx.x;
  const unsigned v = (t < NB) ? bsum[t] : 0u;
  sd[t] = v;
  __syncthreads();
  for (int off = 1; off < 1024; off <<= 1) {
    const unsigned u = (t >= off) ? sd[t - off] : 0u;
    __syncthreads();
    sd[t] += u;
    __syncthreads();
  }
  if (t < NB) bsum[t] = sd[t] - v;   // exclusive
}

// ------- scan pass C: rowptr + cursor + dinv (cursor aliases degpad, in-place) -------
__global__ __launch_bounds__(256) void k_scanC(const unsigned* __restrict__ degpad,
                                               int* __restrict__ rowptr,
                                               int* __restrict__ cursor,
                                               float* __restrict__ dinv,
                                               const unsigned* __restrict__ bexcl,
                                               int N, int E) {
  __shared__ unsigned sd[256];
  const int t = threadIdx.x, b = blockIdx.x;
  const int i0 = b * 1024 + t * 4;
  const uint4 d = *reinterpret_cast<const uint4*>(&degpad[i0]);   // read BEFORE cursor overwrite
  const unsigned dd[4] = {d.x, d.y, d.z, d.w};
  const unsigned p1 = d.x, p2 = p1 + d.y, p3 = p2 + d.z, tt = p3 + d.w;
  sd[t] = tt;
  __syncthreads();
  for (int off = 1; off < 256; off <<= 1) {
    const unsigned u = (t >= off) ? sd[t - off] : 0u;
    __syncthreads();
    sd[t] += u;
    __syncthreads();
  }
  const unsigned base = bexcl[b] + (sd[t] - tt);
  const unsigned r[4] = {base, base + p1, base + p2, base + p3};
#pragma unroll
  for (int k = 0; k < 4; ++k) {
    const int i = i0 + k;
    if (i < N) {
      rowptr[i] = (int)r[k];
      cursor[i] = (int)r[k];
      dinv[i] = rsqrtf((float)dd[k] + 1.0f);   // +1 = self loop
    }
  }
  if (b == 0 && t == 0) rowptr[N] = E;
}

// ---------------- bin fill: esrc sorted-by-dst via cursor atomics ----------------
__global__ void k_binfill(const int* __restrict__ src, const int* __restrict__ dst,
                          int* __restrict__ cursor, int* __restrict__ esrc, int E) {
  const int i = blockIdx.x * blockDim.x + threadIdx.x;
  if (i < E) {
    const int p = atomicAdd(&cursor[dst[i]], 1);
    esrc[p] = src[i];
  }
}

// ---- gather: one wave per node, atomic-free; h' rows bf16 (256B); fused epilogue ----
__global__ __launch_bounds__(256) void k_gather(const uint32_t* __restrict__ hB,
                                                const float* __restrict__ dinv,
                                                const int* __restrict__ rowptr,
                                                const int* __restrict__ esrc,
                                                const float* __restrict__ bias,
                                                float* __restrict__ out, int N) {
  const int lane = threadIdx.x & 63;
  const int v = (int)((blockIdx.x * blockDim.x + threadIdx.x) >> 6);
  if (v >= N) return;
  // self term: h'[v] (since dv*dv*h[v] = dv*h'[v], and final scale by dv happens below)
  uint32_t u = hB[(size_t)v * (F / 2) + lane];
  float a0 = __uint_as_float(u << 16);
  float a1 = __uint_as_float(u & 0xffff0000u);
  const int beg = rowptr[v], end = rowptr[v + 1];
  for (int j0 = beg; j0 < end; j0 += 64) {
    const int cnt = min(64, end - j0);
    const int myS = (j0 + lane < end) ? esrc[j0 + lane] : 0;
    for (int k = 0; k < cnt; ++k) {
      const int s = __shfl(myS, k);
      const uint32_t us = hB[(size_t)s * (F / 2) + lane];
      a0 += __uint_as_float(us << 16);
      a1 += __uint_as_float(us & 0xffff0000u);
    }
  }
  const float dv = dinv[v];
  const int c = lane * 2;
  const float2 bv = *reinterpret_cast<const float2*>(&bias[c]);
  float2 r;
  r.x = fmaxf(fmaf(dv, a0, bv.x), 0.f);
  r.y = fmaxf(fmaf(dv, a1, bv.y), 0.f);
  *reinterpret_cast<float2*>(&out[(size_t)v * F + c]) = r;
}

extern "C" void kernel_launch(void* const* d_in, const int* in_sizes, int n_in,
                              void* d_out, int out_size, void* d_ws, size_t ws_size,
                              hipStream_t stream) {
  const float* x  = (const float*)d_in[0];
  const int*   ei = (const int*)d_in[1];
  const float* W  = (const float*)d_in[2];
  const float* b  = (const float*)d_in[3];
  float* out = (float*)d_out;

  const int N = in_sizes[0] / F;   // 100000
  const int E = in_sizes[1] / 2;   // 1600000
  const int* srcA = ei;
  const int* dstA = ei + E;

  const int NB = (N + 1023) / 1024;       // 98
  const int Npad = NB * 1024;

  auto aln = [](size_t v) { return (v + 255) & ~(size_t)255; };
  char* base = (char*)d_ws;
  size_t off = 0;
  uint32_t* hB = (uint32_t*)(base + off);     off += aln((size_t)N * (F / 2) * sizeof(uint32_t));
  int* esrc = (int*)(base + off);             off += aln((size_t)E * sizeof(int));
  float* dinv = (float*)(base + off);         off += aln((size_t)N * sizeof(float));
  int* rowptr = (int*)(base + off);           off += aln((size_t)(N + 1) * sizeof(int));
  unsigned* degpad = (unsigned*)(base + off); off += aln((size_t)Npad * sizeof(unsigned));
  unsigned* bsum = (unsigned*)(base + off);   off += aln(1024 * sizeof(unsigned));

  int* cursor = (int*)degpad;   // aliased: scanC reads deg then writes cursor in place

  hipMemsetAsync(degpad, 0, (size_t)Npad * sizeof(unsigned), stream);
  k_deg<<<(E + 255) / 256, 256, 0, stream>>>(dstA, degpad, E);
  k_scanA<<<NB, 256, 0, stream>>>(degpad, bsum);
  k_scanB<<<1, 1024, 0, stream>>>(bsum, NB);
  k_scanC<<<NB, 256, 0, stream>>>(degpad, rowptr, cursor, dinv, bsum, N, E);
  k_binfill<<<(E + 255) / 256, 256, 0, stream>>>(srcA, dstA, cursor, esrc, E);
  k_gemm<<<(N + BM - 1) / BM, 256, 0, stream>>>(x, W, dinv, hB, N);
  k_gather<<<(N * 64 + 255) / 256, 256, 0, stream>>>(hB, dinv, rowptr, esrc, b, out, N);
}

// Round 6
// 422.000 us; speedup vs baseline: 2.1402x; 1.1015x over previous
//
#include <hip/hip_runtime.h>

#define F 128
#define BM 64
#define CH 4096   // edges per k_bucket/k_fine block
#define BSH 10    // bucket = dst >> BSH  (1024 nodes/bucket, matches scanA block)

// round-to-nearest-even f32 -> bf16 bits
__device__ inline uint32_t bfbits(float f) {
  uint32_t x = __float_as_uint(f);
  return (x + 0x7fffu + ((x >> 16) & 1u)) >> 16;
}

// ---------------- GEMM: h' = dinv[row] * (x @ W), stored bf16 ----------------
__global__ __launch_bounds__(256) void k_gemm(const float* __restrict__ x,
                                              const float* __restrict__ W,
                                              const float* __restrict__ dinv,
                                              uint32_t* __restrict__ hB, int N) {
  __shared__ float Xs[BM][F + 4];
  __shared__ float Ws[32][F + 4];
  const int t = threadIdx.x;
  const int row0 = blockIdx.x * BM;

  {
    const int r = t >> 5;
    const int c4 = t & 31;
#pragma unroll
    for (int p = 0; p < 8; ++p) {
      const int rr = p * 8 + r;
      const int grow = row0 + rr;
      float4 v = make_float4(0.f, 0.f, 0.f, 0.f);
      if (grow < N) v = *reinterpret_cast<const float4*>(&x[(size_t)grow * F + c4 * 4]);
      *reinterpret_cast<float4*>(&Xs[rr][c4 * 4]) = v;
    }
  }

  float acc[4][8];
#pragma unroll
  for (int i = 0; i < 4; ++i)
#pragma unroll
    for (int j = 0; j < 8; ++j) acc[i][j] = 0.f;

  const int cg = (t & 15) * 8;
  const int rg = (t >> 4) * 4;

  for (int k0 = 0; k0 < F; k0 += 32) {
    __syncthreads();
    {
      const int r = t >> 5;
      const int c4 = t & 31;
#pragma unroll
      for (int p = 0; p < 4; ++p) {
        const int kk = p * 8 + r;
        float4 v = *reinterpret_cast<const float4*>(&W[(size_t)(k0 + kk) * F + c4 * 4]);
        *reinterpret_cast<float4*>(&Ws[kk][c4 * 4]) = v;
      }
    }
    __syncthreads();
#pragma unroll
    for (int kk = 0; kk < 32; ++kk) {
      float xv[4];
#pragma unroll
      for (int i = 0; i < 4; ++i) xv[i] = Xs[rg + i][k0 + kk];
      const float4 w0 = *reinterpret_cast<const float4*>(&Ws[kk][cg]);
      const float4 w1 = *reinterpret_cast<const float4*>(&Ws[kk][cg + 4]);
      const float wv[8] = {w0.x, w0.y, w0.z, w0.w, w1.x, w1.y, w1.z, w1.w};
#pragma unroll
      for (int i = 0; i < 4; ++i)
#pragma unroll
        for (int j = 0; j < 8; ++j) acc[i][j] = fmaf(xv[i], wv[j], acc[i][j]);
    }
  }

#pragma unroll
  for (int i = 0; i < 4; ++i) {
    const int grow = row0 + rg + i;
    if (grow < N) {
      const float dv = dinv[grow];
      uint32_t p0 = bfbits(acc[i][0] * dv) | (bfbits(acc[i][1] * dv) << 16);
      uint32_t p1 = bfbits(acc[i][2] * dv) | (bfbits(acc[i][3] * dv) << 16);
      uint32_t p2 = bfbits(acc[i][4] * dv) | (bfbits(acc[i][5] * dv) << 16);
      uint32_t p3 = bfbits(acc[i][6] * dv) | (bfbits(acc[i][7] * dv) << 16);
      uint4 st = make_uint4(p0, p1, p2, p3);
      *reinterpret_cast<uint4*>(&hB[(size_t)grow * (F / 2) + cg / 2]) = st;
    }
  }
}

// ---------------- degree count ----------------
__global__ void k_deg(const int* __restrict__ dst, unsigned* __restrict__ deg, int E) {
  const int i = blockIdx.x * blockDim.x + threadIdx.x;
  if (i < E) atomicAdd(&deg[dst[i]], 1u);
}

// ---------------- scan pass A: per-block (1024 elems) sums == bucket counts ----------
__global__ __launch_bounds__(256) void k_scanA(const unsigned* __restrict__ degpad,
                                               unsigned* __restrict__ bsum) {
  __shared__ unsigned sd[256];
  const int t = threadIdx.x, b = blockIdx.x;
  const uint4 d = *reinterpret_cast<const uint4*>(&degpad[b * 1024 + t * 4]);
  sd[t] = d.x + d.y + d.z + d.w;
  __syncthreads();
  for (int off = 128; off > 0; off >>= 1) {
    if (t < off) sd[t] += sd[t + off];
    __syncthreads();
  }
  if (t == 0) bsum[b] = sd[0];
}

// ---------------- scan pass B: exclusive scan of bucket counts ----------------
__global__ __launch_bounds__(1024) void k_scanB(unsigned* __restrict__ bsum, int NB) {
  __shared__ unsigned sd[1024];
  const int t = threadIdx.x;
  const unsigned v = (t < NB) ? bsum[t] : 0u;
  sd[t] = v;
  __syncthreads();
  for (int off = 1; off < 1024; off <<= 1) {
    const unsigned u = (t >= off) ? sd[t - off] : 0u;
    __syncthreads();
    sd[t] += u;
    __syncthreads();
  }
  if (t < NB) bsum[t] = sd[t] - v;   // exclusive
}

// ------- scan pass C: rowptr + cursor + dinv (cursor aliases degpad, in-place) -------
__global__ __launch_bounds__(256) void k_scanC(const unsigned* __restrict__ degpad,
                                               int* __restrict__ rowptr,
                                               int* __restrict__ cursor,
                                               float* __restrict__ dinv,
                                               const unsigned* __restrict__ bexcl,
                                               int N, int E) {
  __shared__ unsigned sd[256];
  const int t = threadIdx.x, b = blockIdx.x;
  const int i0 = b * 1024 + t * 4;
  const uint4 d = *reinterpret_cast<const uint4*>(&degpad[i0]);   // read BEFORE cursor overwrite
  const unsigned dd[4] = {d.x, d.y, d.z, d.w};
  const unsigned p1 = d.x, p2 = p1 + d.y, p3 = p2 + d.z, tt = p3 + d.w;
  sd[t] = tt;
  __syncthreads();
  for (int off = 1; off < 256; off <<= 1) {
    const unsigned u = (t >= off) ? sd[t - off] : 0u;
    __syncthreads();
    sd[t] += u;
    __syncthreads();
  }
  const unsigned base = bexcl[b] + (sd[t] - tt);
  const unsigned r[4] = {base, base + p1, base + p2, base + p3};
#pragma unroll
  for (int k = 0; k < 4; ++k) {
    const int i = i0 + k;
    if (i < N) {
      rowptr[i] = (int)r[k];
      cursor[i] = (int)r[k];
      dinv[i] = rsqrtf((float)dd[k] + 1.0f);   // +1 = self loop
    }
  }
  if (b == 0 && t == 0) rowptr[N] = E;
}

// ---- bucket pass: LDS counting-sort chunk by dst>>BSH, coalesced grouped write ----
// pairs[] gets packed (src<<BSH | dstLow), grouped by bucket. bcur starts as the
// exclusive bucket scan (bsum after scanB) and ends as the region END offsets.
__global__ __launch_bounds__(256) void k_bucket(const int* __restrict__ src,
                                                const int* __restrict__ dst,
                                                unsigned* __restrict__ bcur,
                                                uint32_t* __restrict__ pairs,
                                                int E, int nbk) {
  __shared__ uint32_t sorted[CH];
  __shared__ unsigned hist[128], starts[128], cur[128], gb[128];
  const int t = threadIdx.x;
  const int c0 = blockIdx.x * CH;

  if (t < 128) hist[t] = 0;
  __syncthreads();

  uint32_t pk[16];
  unsigned bk[16];
#pragma unroll
  for (int k = 0; k < 16; ++k) {
    const int i = c0 + k * 256 + t;
    if (i < E) {
      const unsigned s = (unsigned)src[i], d = (unsigned)dst[i];
      bk[k] = d >> BSH;
      pk[k] = (s << BSH) | (d & ((1u << BSH) - 1u));
      atomicAdd(&hist[bk[k]], 1u);
    } else bk[k] = 0xffffffffu;
  }
  __syncthreads();

  // inclusive scan of hist -> cur, then starts = exclusive
  if (t < 128) cur[t] = hist[t];
  __syncthreads();
  for (int off = 1; off < 128; off <<= 1) {
    unsigned u = 0;
    if (t < 128 && t >= off) u = cur[t - off];
    __syncthreads();
    if (t < 128) cur[t] += u;
    __syncthreads();
  }
  if (t < 128) starts[t] = cur[t] - hist[t];
  __syncthreads();
  if (t < 128) cur[t] = starts[t];
  if (t < nbk && hist[t] > 0) gb[t] = atomicAdd(&bcur[t], hist[t]);
  __syncthreads();

#pragma unroll
  for (int k = 0; k < 16; ++k) {
    if (bk[k] != 0xffffffffu) {
      const unsigned p = atomicAdd(&cur[bk[k]], 1u);
      sorted[p] = pk[k];
    }
  }
  __syncthreads();

  const int cnt = (c0 + CH <= E) ? CH : (E - c0);
  for (int idx = t; idx < cnt; idx += 256) {
    int lo = 0, hi = nbk - 1;             // largest b with starts[b] <= idx
    while (lo < hi) {
      const int mid = (lo + hi + 1) >> 1;
      if ((int)starts[mid] <= idx) lo = mid; else hi = mid - 1;
    }
    pairs[gb[lo] + (idx - starts[lo])] = sorted[idx];
  }
}

// ---- fine pass: linear over bucket-grouped pairs; writes land in L2-local windows ----
__global__ __launch_bounds__(256) void k_fine(const uint32_t* __restrict__ pairs,
                                              const unsigned* __restrict__ bends,
                                              int* __restrict__ cursor,
                                              int* __restrict__ esrc, int E, int nbk) {
  __shared__ unsigned ends[128];
  const int t = threadIdx.x;
  if (t < 128) ends[t] = (t < nbk) ? bends[t] : (unsigned)E;
  __syncthreads();
  const int c0 = blockIdx.x * CH;
#pragma unroll 4
  for (int k = 0; k < 16; ++k) {
    const int idx = c0 + k * 256 + t;
    if (idx < E) {
      const uint32_t pk = pairs[idx];
      int lo = 0, hi = nbk - 1;           // smallest b with idx < ends[b]
      while (lo < hi) {
        const int mid = (lo + hi) >> 1;
        if ((unsigned)idx < ends[mid]) hi = mid; else lo = mid + 1;
      }
      const int d = (lo << BSH) + (int)(pk & ((1u << BSH) - 1u));
      const int s = (int)(pk >> BSH);
      const int p = atomicAdd(&cursor[d], 1);
      esrc[p] = s;
    }
  }
}

// ---- gather: one wave per node, atomic-free; h' rows bf16 (256B); fused epilogue ----
__global__ __launch_bounds__(256) void k_gather(const uint32_t* __restrict__ hB,
                                                const float* __restrict__ dinv,
                                                const int* __restrict__ rowptr,
                                                const int* __restrict__ esrc,
                                                const float* __restrict__ bias,
                                                float* __restrict__ out, int N) {
  const int lane = threadIdx.x & 63;
  const int v = (int)((blockIdx.x * blockDim.x + threadIdx.x) >> 6);
  if (v >= N) return;
  uint32_t u = hB[(size_t)v * (F / 2) + lane];
  float a0 = __uint_as_float(u << 16);
  float a1 = __uint_as_float(u & 0xffff0000u);
  const int beg = rowptr[v], end = rowptr[v + 1];
  for (int j0 = beg; j0 < end; j0 += 64) {
    const int cnt = min(64, end - j0);
    const int myS = (j0 + lane < end) ? esrc[j0 + lane] : 0;
    for (int k = 0; k < cnt; ++k) {
      const int s = __shfl(myS, k);
      const uint32_t us = hB[(size_t)s * (F / 2) + lane];
      a0 += __uint_as_float(us << 16);
      a1 += __uint_as_float(us & 0xffff0000u);
    }
  }
  const float dv = dinv[v];
  const int c = lane * 2;
  const float2 bv = *reinterpret_cast<const float2*>(&bias[c]);
  float2 r;
  r.x = fmaxf(fmaf(dv, a0, bv.x), 0.f);
  r.y = fmaxf(fmaf(dv, a1, bv.y), 0.f);
  *reinterpret_cast<float2*>(&out[(size_t)v * F + c]) = r;
}

extern "C" void kernel_launch(void* const* d_in, const int* in_sizes, int n_in,
                              void* d_out, int out_size, void* d_ws, size_t ws_size,
                              hipStream_t stream) {
  const float* x  = (const float*)d_in[0];
  const int*   ei = (const int*)d_in[1];
  const float* W  = (const float*)d_in[2];
  const float* b  = (const float*)d_in[3];
  float* out = (float*)d_out;

  const int N = in_sizes[0] / F;   // 100000
  const int E = in_sizes[1] / 2;   // 1600000
  const int* srcA = ei;
  const int* dstA = ei + E;

  const int NB = (N + 1023) / 1024;       // 98 buckets (dst>>10)
  const int Npad = NB * 1024;
  const int NCH = (E + CH - 1) / CH;      // 391 chunks

  auto aln = [](size_t v) { return (v + 255) & ~(size_t)255; };
  char* base = (char*)d_ws;
  size_t off = 0;
  uint32_t* hB = (uint32_t*)(base + off);     off += aln((size_t)N * (F / 2) * sizeof(uint32_t));
  int* esrc = (int*)(base + off);             off += aln((size_t)E * sizeof(int));
  uint32_t* pairs = (uint32_t*)(base + off);  off += aln((size_t)E * sizeof(uint32_t));
  float* dinv = (float*)(base + off);         off += aln((size_t)N * sizeof(float));
  int* rowptr = (int*)(base + off);           off += aln((size_t)(N + 1) * sizeof(int));
  unsigned* degpad = (unsigned*)(base + off); off += aln((size_t)Npad * sizeof(unsigned));
  unsigned* bsum = (unsigned*)(base + off);   off += aln(1024 * sizeof(unsigned));

  int* cursor = (int*)degpad;   // aliased: scanC reads deg then writes cursor in place

  hipMemsetAsync(degpad, 0, (size_t)Npad * sizeof(unsigned), stream);
  k_deg<<<(E + 255) / 256, 256, 0, stream>>>(dstA, degpad, E);
  k_scanA<<<NB, 256, 0, stream>>>(degpad, bsum);
  k_scanB<<<1, 1024, 0, stream>>>(bsum, NB);
  k_scanC<<<NB, 256, 0, stream>>>(degpad, rowptr, cursor, dinv, bsum, N, E);
  k_bucket<<<NCH, 256, 0, stream>>>(srcA, dstA, bsum, pairs, E, NB);   // bsum -> region ends
  k_fine<<<NCH, 256, 0, stream>>>(pairs, bsum, cursor, esrc, E, NB);
  k_gemm<<<(N + BM - 1) / BM, 256, 0, stream>>>(x, W, dinv, hB, N);
  k_gather<<<(N * 64 + 255) / 256, 256, 0, stream>>>(hB, dinv, rowptr, esrc, b, out, N);
}

// Round 7
// 346.164 us; speedup vs baseline: 2.6091x; 1.2191x over previous
//
#include <hip/hip_runtime.h>

#define F 128
#define BM 64
#define CH 4096   // edges per k_bucket block
#define BSH 10    // bucket = dst >> BSH (1024 nodes/bucket)

// round-to-nearest-even f32 -> bf16 bits
__device__ inline uint32_t bfbits(float f) {
  uint32_t x = __float_as_uint(f);
  return (x + 0x7fffu + ((x >> 16) & 1u)) >> 16;
}

// ---------------- GEMM: h' = dinv[row] * (x @ W), stored bf16 ----------------
__global__ __launch_bounds__(256) void k_gemm(const float* __restrict__ x,
                                              const float* __restrict__ W,
                                              const float* __restrict__ dinv,
                                              uint32_t* __restrict__ hB, int N) {
  __shared__ float Xs[BM][F + 4];
  __shared__ float Ws[32][F + 4];
  const int t = threadIdx.x;
  const int row0 = blockIdx.x * BM;

  {
    const int r = t >> 5;
    const int c4 = t & 31;
#pragma unroll
    for (int p = 0; p < 8; ++p) {
      const int rr = p * 8 + r;
      const int grow = row0 + rr;
      float4 v = make_float4(0.f, 0.f, 0.f, 0.f);
      if (grow < N) v = *reinterpret_cast<const float4*>(&x[(size_t)grow * F + c4 * 4]);
      *reinterpret_cast<float4*>(&Xs[rr][c4 * 4]) = v;
    }
  }

  float acc[4][8];
#pragma unroll
  for (int i = 0; i < 4; ++i)
#pragma unroll
    for (int j = 0; j < 8; ++j) acc[i][j] = 0.f;

  const int cg = (t & 15) * 8;
  const int rg = (t >> 4) * 4;

  for (int k0 = 0; k0 < F; k0 += 32) {
    __syncthreads();
    {
      const int r = t >> 5;
      const int c4 = t & 31;
#pragma unroll
      for (int p = 0; p < 4; ++p) {
        const int kk = p * 8 + r;
        float4 v = *reinterpret_cast<const float4*>(&W[(size_t)(k0 + kk) * F + c4 * 4]);
        *reinterpret_cast<float4*>(&Ws[kk][c4 * 4]) = v;
      }
    }
    __syncthreads();
#pragma unroll
    for (int kk = 0; kk < 32; ++kk) {
      float xv[4];
#pragma unroll
      for (int i = 0; i < 4; ++i) xv[i] = Xs[rg + i][k0 + kk];
      const float4 w0 = *reinterpret_cast<const float4*>(&Ws[kk][cg]);
      const float4 w1 = *reinterpret_cast<const float4*>(&Ws[kk][cg + 4]);
      const float wv[8] = {w0.x, w0.y, w0.z, w0.w, w1.x, w1.y, w1.z, w1.w};
#pragma unroll
      for (int i = 0; i < 4; ++i)
#pragma unroll
        for (int j = 0; j < 8; ++j) acc[i][j] = fmaf(xv[i], wv[j], acc[i][j]);
    }
  }

#pragma unroll
  for (int i = 0; i < 4; ++i) {
    const int grow = row0 + rg + i;
    if (grow < N) {
      const float dv = dinv[grow];
      uint32_t p0 = bfbits(acc[i][0] * dv) | (bfbits(acc[i][1] * dv) << 16);
      uint32_t p1 = bfbits(acc[i][2] * dv) | (bfbits(acc[i][3] * dv) << 16);
      uint32_t p2 = bfbits(acc[i][4] * dv) | (bfbits(acc[i][5] * dv) << 16);
      uint32_t p3 = bfbits(acc[i][6] * dv) | (bfbits(acc[i][7] * dv) << 16);
      uint4 st = make_uint4(p0, p1, p2, p3);
      *reinterpret_cast<uint4*>(&hB[(size_t)grow * (F / 2) + cg / 2]) = st;
    }
  }
}

// ---------------- bucket-count histogram (98 bins, LDS-local) ----------------
__global__ __launch_bounds__(256) void k_hist(const int* __restrict__ dst,
                                              unsigned* __restrict__ bcnt, int E) {
  __shared__ unsigned h[128];
  const int t = threadIdx.x;
  if (t < 128) h[t] = 0;
  __syncthreads();
  for (int i = blockIdx.x * 256 + t; i < E; i += gridDim.x * 256)
    atomicAdd(&h[(unsigned)dst[i] >> BSH], 1u);
  __syncthreads();
  if (t < 128 && h[t]) atomicAdd(&bcnt[t], h[t]);
}

// ------- exclusive scan of bucket counts -> bstart[nbk+1]; copy to bcur -------
__global__ __launch_bounds__(128) void k_scanB2(const unsigned* __restrict__ bcnt,
                                                unsigned* __restrict__ bstart,
                                                unsigned* __restrict__ bcur,
                                                int nbk, int E) {
  __shared__ unsigned sd[128];
  const int t = threadIdx.x;
  const unsigned v = (t < nbk) ? bcnt[t] : 0u;
  sd[t] = v;
  __syncthreads();
  for (int off = 1; off < 128; off <<= 1) {
    const unsigned u = (t >= off) ? sd[t - off] : 0u;
    __syncthreads();
    sd[t] += u;
    __syncthreads();
  }
  if (t < nbk) { const unsigned s = sd[t] - v; bstart[t] = s; bcur[t] = s; }
  if (t == 0) bstart[nbk] = (unsigned)E;
}

// ---- bucket pass: LDS counting-sort chunk by dst>>BSH, coalesced grouped write ----
__global__ __launch_bounds__(256) void k_bucket(const int* __restrict__ src,
                                                const int* __restrict__ dst,
                                                unsigned* __restrict__ bcur,
                                                uint32_t* __restrict__ pairs,
                                                int E, int nbk) {
  __shared__ uint32_t sorted[CH];
  __shared__ unsigned hist[128], starts[128], cur[128], gb[128];
  const int t = threadIdx.x;
  const int c0 = blockIdx.x * CH;

  if (t < 128) hist[t] = 0;
  __syncthreads();

  uint32_t pk[16];
  unsigned bk[16];
#pragma unroll
  for (int k = 0; k < 16; ++k) {
    const int i = c0 + k * 256 + t;
    if (i < E) {
      const unsigned s = (unsigned)src[i], d = (unsigned)dst[i];
      bk[k] = d >> BSH;
      pk[k] = (s << BSH) | (d & ((1u << BSH) - 1u));
      atomicAdd(&hist[bk[k]], 1u);
    } else bk[k] = 0xffffffffu;
  }
  __syncthreads();

  if (t < 128) cur[t] = hist[t];
  __syncthreads();
  for (int off = 1; off < 128; off <<= 1) {
    unsigned u = 0;
    if (t < 128 && t >= off) u = cur[t - off];
    __syncthreads();
    if (t < 128) cur[t] += u;
    __syncthreads();
  }
  if (t < 128) starts[t] = cur[t] - hist[t];
  __syncthreads();
  if (t < 128) cur[t] = starts[t];
  if (t < nbk && hist[t] > 0) gb[t] = atomicAdd(&bcur[t], hist[t]);
  __syncthreads();

#pragma unroll
  for (int k = 0; k < 16; ++k) {
    if (bk[k] != 0xffffffffu) {
      const unsigned p = atomicAdd(&cur[bk[k]], 1u);
      sorted[p] = pk[k];
    }
  }
  __syncthreads();

  const int cnt = (c0 + CH <= E) ? CH : (E - c0);
  for (int idx = t; idx < cnt; idx += 256) {
    int lo = 0, hi = nbk - 1;
    while (lo < hi) {
      const int mid = (lo + hi + 1) >> 1;
      if ((int)starts[mid] <= idx) lo = mid; else hi = mid - 1;
    }
    pairs[gb[lo] + (idx - starts[lo])] = sorted[idx];
  }
}

// ---- per-bucket: deg-hist + scan + rowptr/dinv + LDS-cursor scatter (no global atomics) ----
__global__ __launch_bounds__(256) void k_pernode(const uint32_t* __restrict__ pairs,
                                                 const unsigned* __restrict__ bstart,
                                                 int* __restrict__ rowptr,
                                                 float* __restrict__ dinv,
                                                 int* __restrict__ esrc,
                                                 int N, int E) {
  __shared__ unsigned hist[1024];
  __shared__ unsigned sd[256];
  const int b = blockIdx.x;
  const int t = threadIdx.x;
  const unsigned beg = bstart[b], end = bstart[b + 1];

  for (int i = t; i < 1024; i += 256) hist[i] = 0;
  __syncthreads();
  for (unsigned i = beg + t; i < end; i += 256)
    atomicAdd(&hist[pairs[i] & 1023u], 1u);
  __syncthreads();

  // exclusive scan of 1024 (4 per thread)
  const unsigned d0 = hist[4 * t], d1 = hist[4 * t + 1], d2 = hist[4 * t + 2], d3 = hist[4 * t + 3];
  const unsigned tt = d0 + d1 + d2 + d3;
  sd[t] = tt;
  __syncthreads();
  for (int off = 1; off < 256; off <<= 1) {
    const unsigned u = (t >= off) ? sd[t - off] : 0u;
    __syncthreads();
    sd[t] += u;
    __syncthreads();
  }
  const unsigned base = sd[t] - tt;
  const unsigned r0 = base, r1 = base + d0, r2 = base + d0 + d1, r3 = base + d0 + d1 + d2;
  hist[4 * t] = r0; hist[4 * t + 1] = r1; hist[4 * t + 2] = r2; hist[4 * t + 3] = r3;

  const int node0 = b << BSH;
  const unsigned dd[4] = {d0, d1, d2, d3};
  const unsigned rr[4] = {r0, r1, r2, r3};
#pragma unroll
  for (int k = 0; k < 4; ++k) {
    const int node = node0 + 4 * t + k;
    if (node < N) {
      rowptr[node] = (int)(beg + rr[k]);
      dinv[node] = rsqrtf((float)dd[k] + 1.0f);   // +1 = self loop
    }
  }
  if (b == 0 && t == 0) rowptr[N] = E;
  __syncthreads();

  // scatter within region via LDS cursors
  for (unsigned i = beg + t; i < end; i += 256) {
    const uint32_t pk = pairs[i];
    const unsigned p = atomicAdd(&hist[pk & 1023u], 1u);
    esrc[beg + p] = (int)(pk >> BSH);
  }
}

// ---- gather: one wave per node, atomic-free; h' rows bf16 (256B); fused epilogue ----
__global__ __launch_bounds__(256) void k_gather(const uint32_t* __restrict__ hB,
                                                const float* __restrict__ dinv,
                                                const int* __restrict__ rowptr,
                                                const int* __restrict__ esrc,
                                                const float* __restrict__ bias,
                                                float* __restrict__ out, int N) {
  const int lane = threadIdx.x & 63;
  const int v = (int)((blockIdx.x * blockDim.x + threadIdx.x) >> 6);
  if (v >= N) return;
  uint32_t u = hB[(size_t)v * (F / 2) + lane];
  float a0 = __uint_as_float(u << 16);
  float a1 = __uint_as_float(u & 0xffff0000u);
  const int beg = rowptr[v], end = rowptr[v + 1];
  for (int j0 = beg; j0 < end; j0 += 64) {
    const int cnt = min(64, end - j0);
    const int myS = (j0 + lane < end) ? esrc[j0 + lane] : 0;
    for (int k = 0; k < cnt; ++k) {
      const int s = __shfl(myS, k);
      const uint32_t us = hB[(size_t)s * (F / 2) + lane];
      a0 += __uint_as_float(us << 16);
      a1 += __uint_as_float(us & 0xffff0000u);
    }
  }
  const float dv = dinv[v];
  const int c = lane * 2;
  const float2 bv = *reinterpret_cast<const float2*>(&bias[c]);
  float2 r;
  r.x = fmaxf(fmaf(dv, a0, bv.x), 0.f);
  r.y = fmaxf(fmaf(dv, a1, bv.y), 0.f);
  *reinterpret_cast<float2*>(&out[(size_t)v * F + c]) = r;
}

extern "C" void kernel_launch(void* const* d_in, const int* in_sizes, int n_in,
                              void* d_out, int out_size, void* d_ws, size_t ws_size,
                              hipStream_t stream) {
  const float* x  = (const float*)d_in[0];
  const int*   ei = (const int*)d_in[1];
  const float* W  = (const float*)d_in[2];
  const float* b  = (const float*)d_in[3];
  float* out = (float*)d_out;

  const int N = in_sizes[0] / F;   // 100000
  const int E = in_sizes[1] / 2;   // 1600000
  const int* srcA = ei;
  const int* dstA = ei + E;

  const int NB = (N + 1023) / 1024;       // 98 buckets
  const int NCH = (E + CH - 1) / CH;      // 391 chunks

  auto aln = [](size_t v) { return (v + 255) & ~(size_t)255; };
  char* base = (char*)d_ws;
  size_t off = 0;
  uint32_t* hB = (uint32_t*)(base + off);     off += aln((size_t)N * (F / 2) * sizeof(uint32_t));
  int* esrc = (int*)(base + off);             off += aln((size_t)E * sizeof(int));
  uint32_t* pairs = (uint32_t*)(base + off);  off += aln((size_t)E * sizeof(uint32_t));
  float* dinv = (float*)(base + off);         off += aln((size_t)N * sizeof(float));
  int* rowptr = (int*)(base + off);           off += aln((size_t)(N + 1) * sizeof(int));
  unsigned* bcnt = (unsigned*)(base + off);   off += aln(128 * sizeof(unsigned));
  unsigned* bstart = (unsigned*)(base + off); off += aln(129 * sizeof(unsigned));
  unsigned* bcur = (unsigned*)(base + off);   off += aln(128 * sizeof(unsigned));

  hipMemsetAsync(bcnt, 0, 128 * sizeof(unsigned), stream);
  k_hist<<<256, 256, 0, stream>>>(dstA, bcnt, E);
  k_scanB2<<<1, 128, 0, stream>>>(bcnt, bstart, bcur, NB, E);
  k_bucket<<<NCH, 256, 0, stream>>>(srcA, dstA, bcur, pairs, E, NB);
  k_pernode<<<NB, 256, 0, stream>>>(pairs, bstart, rowptr, dinv, esrc, N, E);
  k_gemm<<<(N + BM - 1) / BM, 256, 0, stream>>>(x, W, dinv, hB, N);
  k_gather<<<(N * 64 + 255) / 256, 256, 0, stream>>>(hB, dinv, rowptr, esrc, b, out, N);
}

// Round 8
// 289.318 us; speedup vs baseline: 3.1218x; 1.1965x over previous
//
#include <hip/hip_runtime.h>

#define F 128
#define BM 64
#define CH 4096   // edges per k_bucket block
#define BSH 9     // bucket = dst >> BSH (512 nodes/bucket)
#define BMSK ((1u << BSH) - 1u)

// round-to-nearest-even f32 -> bf16 bits
__device__ inline uint32_t bfbits(float f) {
  uint32_t x = __float_as_uint(f);
  return (x + 0x7fffu + ((x >> 16) & 1u)) >> 16;
}
__device__ inline float blo(uint32_t u) { return __uint_as_float(u << 16); }
__device__ inline float bhi(uint32_t u) { return __uint_as_float(u & 0xffff0000u); }

// ---------------- GEMM: h' = dinv[row] * (x @ W), stored bf16 ----------------
__global__ __launch_bounds__(256) void k_gemm(const float* __restrict__ x,
                                              const float* __restrict__ W,
                                              const float* __restrict__ dinv,
                                              uint32_t* __restrict__ hB, int N) {
  __shared__ float Xs[BM][F + 4];
  __shared__ float Ws[32][F + 4];
  const int t = threadIdx.x;
  const int row0 = blockIdx.x * BM;

  {
    const int r = t >> 5;
    const int c4 = t & 31;
#pragma unroll
    for (int p = 0; p < 8; ++p) {
      const int rr = p * 8 + r;
      const int grow = row0 + rr;
      float4 v = make_float4(0.f, 0.f, 0.f, 0.f);
      if (grow < N) v = *reinterpret_cast<const float4*>(&x[(size_t)grow * F + c4 * 4]);
      *reinterpret_cast<float4*>(&Xs[rr][c4 * 4]) = v;
    }
  }

  float acc[4][8];
#pragma unroll
  for (int i = 0; i < 4; ++i)
#pragma unroll
    for (int j = 0; j < 8; ++j) acc[i][j] = 0.f;

  const int cg = (t & 15) * 8;
  const int rg = (t >> 4) * 4;

  for (int k0 = 0; k0 < F; k0 += 32) {
    __syncthreads();
    {
      const int r = t >> 5;
      const int c4 = t & 31;
#pragma unroll
      for (int p = 0; p < 4; ++p) {
        const int kk = p * 8 + r;
        float4 v = *reinterpret_cast<const float4*>(&W[(size_t)(k0 + kk) * F + c4 * 4]);
        *reinterpret_cast<float4*>(&Ws[kk][c4 * 4]) = v;
      }
    }
    __syncthreads();
#pragma unroll
    for (int kk = 0; kk < 32; ++kk) {
      float xv[4];
#pragma unroll
      for (int i = 0; i < 4; ++i) xv[i] = Xs[rg + i][k0 + kk];
      const float4 w0 = *reinterpret_cast<const float4*>(&Ws[kk][cg]);
      const float4 w1 = *reinterpret_cast<const float4*>(&Ws[kk][cg + 4]);
      const float wv[8] = {w0.x, w0.y, w0.z, w0.w, w1.x, w1.y, w1.z, w1.w};
#pragma unroll
      for (int i = 0; i < 4; ++i)
#pragma unroll
        for (int j = 0; j < 8; ++j) acc[i][j] = fmaf(xv[i], wv[j], acc[i][j]);
    }
  }

#pragma unroll
  for (int i = 0; i < 4; ++i) {
    const int grow = row0 + rg + i;
    if (grow < N) {
      const float dv = dinv[grow];
      uint32_t p0 = bfbits(acc[i][0] * dv) | (bfbits(acc[i][1] * dv) << 16);
      uint32_t p1 = bfbits(acc[i][2] * dv) | (bfbits(acc[i][3] * dv) << 16);
      uint32_t p2 = bfbits(acc[i][4] * dv) | (bfbits(acc[i][5] * dv) << 16);
      uint32_t p3 = bfbits(acc[i][6] * dv) | (bfbits(acc[i][7] * dv) << 16);
      uint4 st = make_uint4(p0, p1, p2, p3);
      *reinterpret_cast<uint4*>(&hB[(size_t)grow * (F / 2) + cg / 2]) = st;
    }
  }
}

// ---------------- bucket-count histogram (196 bins, LDS-local) ----------------
__global__ __launch_bounds__(256) void k_hist(const int* __restrict__ dst,
                                              unsigned* __restrict__ bcnt, int E) {
  __shared__ unsigned h[256];
  const int t = threadIdx.x;
  h[t] = 0;
  __syncthreads();
  for (int i = blockIdx.x * 256 + t; i < E; i += gridDim.x * 256)
    atomicAdd(&h[(unsigned)dst[i] >> BSH], 1u);
  __syncthreads();
  if (h[t]) atomicAdd(&bcnt[t], h[t]);
}

// ------- exclusive scan of bucket counts -> bstart[nbk+1]; copy to bcur -------
__global__ __launch_bounds__(256) void k_scanB2(const unsigned* __restrict__ bcnt,
                                                unsigned* __restrict__ bstart,
                                                unsigned* __restrict__ bcur,
                                                int nbk, int E) {
  __shared__ unsigned sd[256];
  const int t = threadIdx.x;
  const unsigned v = (t < nbk) ? bcnt[t] : 0u;
  sd[t] = v;
  __syncthreads();
  for (int off = 1; off < 256; off <<= 1) {
    const unsigned u = (t >= off) ? sd[t - off] : 0u;
    __syncthreads();
    sd[t] += u;
    __syncthreads();
  }
  if (t < nbk) { const unsigned s = sd[t] - v; bstart[t] = s; bcur[t] = s; }
  if (t == 0) bstart[nbk] = (unsigned)E;
}

// ---- bucket pass: LDS counting-sort chunk by dst>>BSH, coalesced grouped write ----
__global__ __launch_bounds__(256) void k_bucket(const int* __restrict__ src,
                                                const int* __restrict__ dst,
                                                unsigned* __restrict__ bcur,
                                                uint32_t* __restrict__ pairs,
                                                int E, int nbk) {
  __shared__ uint32_t sorted[CH];
  __shared__ unsigned hist[256], starts[256], cur[256], gb[256];
  const int t = threadIdx.x;
  const int c0 = blockIdx.x * CH;

  hist[t] = 0;
  __syncthreads();

  uint32_t pk[16];
  unsigned bk[16];
#pragma unroll
  for (int k = 0; k < 16; ++k) {
    const int i = c0 + k * 256 + t;
    if (i < E) {
      const unsigned s = (unsigned)src[i], d = (unsigned)dst[i];
      bk[k] = d >> BSH;
      pk[k] = (s << BSH) | (d & BMSK);
      atomicAdd(&hist[bk[k]], 1u);
    } else bk[k] = 0xffffffffu;
  }
  __syncthreads();

  cur[t] = hist[t];
  __syncthreads();
  for (int off = 1; off < 256; off <<= 1) {
    const unsigned u = (t >= off) ? cur[t - off] : 0u;
    __syncthreads();
    cur[t] += u;
    __syncthreads();
  }
  starts[t] = cur[t] - hist[t];
  __syncthreads();
  cur[t] = starts[t];
  if (t < nbk && hist[t] > 0) gb[t] = atomicAdd(&bcur[t], hist[t]);
  __syncthreads();

#pragma unroll
  for (int k = 0; k < 16; ++k) {
    if (bk[k] != 0xffffffffu) {
      const unsigned p = atomicAdd(&cur[bk[k]], 1u);
      sorted[p] = pk[k];
    }
  }
  __syncthreads();

  const int cnt = (c0 + CH <= E) ? CH : (E - c0);
  for (int idx = t; idx < cnt; idx += 256) {
    int lo = 0, hi = nbk - 1;
    while (lo < hi) {
      const int mid = (lo + hi + 1) >> 1;
      if ((int)starts[mid] <= idx) lo = mid; else hi = mid - 1;
    }
    pairs[gb[lo] + (idx - starts[lo])] = sorted[idx];
  }
}

// ---- per-bucket: deg-hist + scan + rowptr/dinv + LDS-cursor scatter (no global atomics) ----
__global__ __launch_bounds__(256) void k_pernode(const uint32_t* __restrict__ pairs,
                                                 const unsigned* __restrict__ bstart,
                                                 int* __restrict__ rowptr,
                                                 float* __restrict__ dinv,
                                                 int* __restrict__ esrc,
                                                 int N, int E) {
  __shared__ unsigned hist[512];
  __shared__ unsigned sd[256];
  const int b = blockIdx.x;
  const int t = threadIdx.x;
  const unsigned beg = bstart[b], end = bstart[b + 1];

  hist[t] = 0; hist[t + 256] = 0;
  __syncthreads();
  for (unsigned i = beg + t; i < end; i += 256)
    atomicAdd(&hist[pairs[i] & BMSK], 1u);
  __syncthreads();

  // exclusive scan of 512 (2 per thread)
  const unsigned d0 = hist[2 * t], d1 = hist[2 * t + 1];
  const unsigned tt = d0 + d1;
  sd[t] = tt;
  __syncthreads();
  for (int off = 1; off < 256; off <<= 1) {
    const unsigned u = (t >= off) ? sd[t - off] : 0u;
    __syncthreads();
    sd[t] += u;
    __syncthreads();
  }
  const unsigned base = sd[t] - tt;
  const unsigned r0 = base, r1 = base + d0;
  hist[2 * t] = r0; hist[2 * t + 1] = r1;

  const int node0 = b << BSH;
  const unsigned dd[2] = {d0, d1};
  const unsigned rr[2] = {r0, r1};
#pragma unroll
  for (int k = 0; k < 2; ++k) {
    const int node = node0 + 2 * t + k;
    if (node < N) {
      rowptr[node] = (int)(beg + rr[k]);
      dinv[node] = rsqrtf((float)dd[k] + 1.0f);   // +1 = self loop
    }
  }
  if (b == 0 && t == 0) rowptr[N] = E;
  __syncthreads();

  // scatter within region via LDS cursors
  for (unsigned i = beg + t; i < end; i += 256) {
    const uint32_t pk = pairs[i];
    const unsigned p = atomicAdd(&hist[pk & BMSK], 1u);
    esrc[beg + p] = (int)(pk >> BSH);
  }
}

// ---- gather: one wave per node, 8-deep MLP, atomic-free, fused epilogue ----
__global__ __launch_bounds__(256) void k_gather(const uint32_t* __restrict__ hB,
                                                const float* __restrict__ dinv,
                                                const int* __restrict__ rowptr,
                                                const int* __restrict__ esrc,
                                                const float* __restrict__ bias,
                                                float* __restrict__ out, int N) {
  const int lane = threadIdx.x & 63;
  const int v = (int)((blockIdx.x * blockDim.x + threadIdx.x) >> 6);
  if (v >= N) return;
  const uint32_t* hL = hB + lane;
  const uint32_t u = hL[(size_t)v << 6];
  float a0 = blo(u), a1 = bhi(u);                 // self term
  float b0 = 0.f, b1 = 0.f, c0 = 0.f, c1 = 0.f, e0 = 0.f, e1 = 0.f;
  const int beg = rowptr[v], end = rowptr[v + 1];
  for (int j0 = beg; j0 < end; j0 += 64) {
    const int cnt = min(64, end - j0);
    const int myS = (j0 + lane < end) ? esrc[j0 + lane] : 0;
    int k = 0;
    for (; k + 8 <= cnt; k += 8) {
      const int s0 = __shfl(myS, k),     s1 = __shfl(myS, k + 1);
      const int s2 = __shfl(myS, k + 2), s3 = __shfl(myS, k + 3);
      const int s4 = __shfl(myS, k + 4), s5 = __shfl(myS, k + 5);
      const int s6 = __shfl(myS, k + 6), s7 = __shfl(myS, k + 7);
      const uint32_t u0 = hL[(size_t)s0 << 6], u1 = hL[(size_t)s1 << 6];
      const uint32_t u2 = hL[(size_t)s2 << 6], u3 = hL[(size_t)s3 << 6];
      const uint32_t u4 = hL[(size_t)s4 << 6], u5 = hL[(size_t)s5 << 6];
      const uint32_t u6 = hL[(size_t)s6 << 6], u7 = hL[(size_t)s7 << 6];
      a0 += blo(u0); a1 += bhi(u0); b0 += blo(u1); b1 += bhi(u1);
      c0 += blo(u2); c1 += bhi(u2); e0 += blo(u3); e1 += bhi(u3);
      a0 += blo(u4); a1 += bhi(u4); b0 += blo(u5); b1 += bhi(u5);
      c0 += blo(u6); c1 += bhi(u6); e0 += blo(u7); e1 += bhi(u7);
    }
    for (; k < cnt; ++k) {
      const int s = __shfl(myS, k);
      const uint32_t us = hL[(size_t)s << 6];
      a0 += blo(us); a1 += bhi(us);
    }
  }
  a0 += b0 + c0 + e0;
  a1 += b1 + c1 + e1;
  const float dv = dinv[v];
  const int c = lane * 2;
  const float2 bv = *reinterpret_cast<const float2*>(&bias[c]);
  float2 r;
  r.x = fmaxf(fmaf(dv, a0, bv.x), 0.f);
  r.y = fmaxf(fmaf(dv, a1, bv.y), 0.f);
  *reinterpret_cast<float2*>(&out[(size_t)v * F + c]) = r;
}

extern "C" void kernel_launch(void* const* d_in, const int* in_sizes, int n_in,
                              void* d_out, int out_size, void* d_ws, size_t ws_size,
                              hipStream_t stream) {
  const float* x  = (const float*)d_in[0];
  const int*   ei = (const int*)d_in[1];
  const float* W  = (const float*)d_in[2];
  const float* b  = (const float*)d_in[3];
  float* out = (float*)d_out;

  const int N = in_sizes[0] / F;   // 100000
  const int E = in_sizes[1] / 2;   // 1600000
  const int* srcA = ei;
  const int* dstA = ei + E;

  const int NB = (N + (1 << BSH) - 1) >> BSH;   // 196 buckets
  const int NCH = (E + CH - 1) / CH;            // 391 chunks

  auto aln = [](size_t v) { return (v + 255) & ~(size_t)255; };
  char* base = (char*)d_ws;
  size_t off = 0;
  uint32_t* hB = (uint32_t*)(base + off);     off += aln((size_t)N * (F / 2) * sizeof(uint32_t));
  int* esrc = (int*)(base + off);             off += aln((size_t)E * sizeof(int));
  uint32_t* pairs = (uint32_t*)(base + off);  off += aln((size_t)E * sizeof(uint32_t));
  float* dinv = (float*)(base + off);         off += aln((size_t)N * sizeof(float));
  int* rowptr = (int*)(base + off);           off += aln((size_t)(N + 1) * sizeof(int));
  unsigned* bcnt = (unsigned*)(base + off);   off += aln(256 * sizeof(unsigned));
  unsigned* bstart = (unsigned*)(base + off); off += aln(257 * sizeof(unsigned));
  unsigned* bcur = (unsigned*)(base + off);   off += aln(256 * sizeof(unsigned));

  hipMemsetAsync(bcnt, 0, 256 * sizeof(unsigned), stream);
  k_hist<<<256, 256, 0, stream>>>(dstA, bcnt, E);
  k_scanB2<<<1, 256, 0, stream>>>(bcnt, bstart, bcur, NB, E);
  k_bucket<<<NCH, 256, 0, stream>>>(srcA, dstA, bcur, pairs, E, NB);
  k_pernode<<<NB, 256, 0, stream>>>(pairs, bstart, rowptr, dinv, esrc, N, E);
  k_gemm<<<(N + BM - 1) / BM, 256, 0, stream>>>(x, W, dinv, hB, N);
  k_gather<<<(N * 64 + 255) / 256, 256, 0, stream>>>(hB, dinv, rowptr, esrc, b, out, N);
}

// Round 9
// 242.502 us; speedup vs baseline: 3.7244x; 1.1931x over previous
//
#include <hip/hip_runtime.h>

#define F 128
#define CH 4096   // edges per k_bucket block
#define BSH 9     // bucket = dst >> BSH (512 nodes/bucket)
#define BMSK ((1u << BSH) - 1u)

typedef __bf16 bf16x8 __attribute__((ext_vector_type(8)));
typedef float f32x4 __attribute__((ext_vector_type(4)));

// round-to-nearest-even f32 -> bf16 bits
__device__ inline uint32_t bfbits(float f) {
  uint32_t x = __float_as_uint(f);
  return (x + 0x7fffu + ((x >> 16) & 1u)) >> 16;
}
__device__ inline float blo(uint32_t u) { return __uint_as_float(u << 16); }
__device__ inline float bhi(uint32_t u) { return __uint_as_float(u & 0xffff0000u); }

// ---------------- GEMM (MFMA bf16): h' = dinv[row] * (x @ W), stored bf16 ----------------
// 4 waves x 16 rows = 64 rows/block. W staged frag-ready in LDS (32 KB).
// Layouts (m89/m91-verified): A row=lane&15,k=(lane>>4)*8+i; B col=lane&15,same k;
// D col=lane&15,row=(lane>>4)*4+reg.
__global__ __launch_bounds__(256) void k_gemm(const float* __restrict__ x,
                                              const float* __restrict__ W,
                                              const float* __restrict__ dinv,
                                              uint32_t* __restrict__ hB, int N) {
  __shared__ uint4 wb[2048];   // [kc][nc][lane] -> 8 bf16 (frag-ready)
  const int t = threadIdx.x;

  // stage W -> LDS as bf16 fragments (W is 64KB, L2-broadcast across blocks)
#pragma unroll
  for (int p = 0; p < 8; ++p) {
    const int s = p * 256 + t;
    const int l = s & 63, nc = (s >> 6) & 7, kc = s >> 9;
    const int kbase = kc * 32 + ((l >> 4) << 3);
    const int col = nc * 16 + (l & 15);
    uint32_t q[4];
#pragma unroll
    for (int ii = 0; ii < 4; ++ii) {
      const uint32_t lo2 = bfbits(W[(size_t)(kbase + 2 * ii) * F + col]);
      const uint32_t hi2 = bfbits(W[(size_t)(kbase + 2 * ii + 1) * F + col]);
      q[ii] = lo2 | (hi2 << 16);
    }
    wb[s] = make_uint4(q[0], q[1], q[2], q[3]);
  }
  __syncthreads();

  const int w = t >> 6, l = t & 63;
  const int r0 = blockIdx.x * 64 + w * 16;
  const int arow = r0 + (l & 15);
  const int kb = (l >> 4) << 3;

  // A fragments: 4 k-chunks, 8 bf16 each, straight from x
  bf16x8 af[4];
#pragma unroll
  for (int kc = 0; kc < 4; ++kc) {
    float4 v0 = make_float4(0.f, 0.f, 0.f, 0.f), v1 = v0;
    if (arow < N) {
      v0 = *reinterpret_cast<const float4*>(&x[(size_t)arow * F + kc * 32 + kb]);
      v1 = *reinterpret_cast<const float4*>(&x[(size_t)arow * F + kc * 32 + kb + 4]);
    }
    const uint4 u = make_uint4(bfbits(v0.x) | (bfbits(v0.y) << 16),
                               bfbits(v0.z) | (bfbits(v0.w) << 16),
                               bfbits(v1.x) | (bfbits(v1.y) << 16),
                               bfbits(v1.z) | (bfbits(v1.w) << 16));
    af[kc] = __builtin_bit_cast(bf16x8, u);
  }

  f32x4 acc[8];
#pragma unroll
  for (int nc = 0; nc < 8; ++nc) acc[nc] = (f32x4){0.f, 0.f, 0.f, 0.f};

#pragma unroll
  for (int kc = 0; kc < 4; ++kc) {
#pragma unroll
    for (int nc = 0; nc < 8; ++nc) {
      const bf16x8 bf = __builtin_bit_cast(bf16x8, wb[(kc * 8 + nc) * 64 + l]);
      acc[nc] = __builtin_amdgcn_mfma_f32_16x16x32_bf16(af[kc], bf, acc[nc], 0, 0, 0);
    }
  }

  // epilogue: *dinv, pack bf16, store
  ushort* hBs = (ushort*)hB;
#pragma unroll
  for (int r = 0; r < 4; ++r) {
    const int row = r0 + ((l >> 4) << 2) + r;
    if (row < N) {
      const float dv = dinv[row];
#pragma unroll
      for (int nc = 0; nc < 8; ++nc)
        hBs[(size_t)row * F + nc * 16 + (l & 15)] = (ushort)bfbits(acc[nc][r] * dv);
    }
  }
}

// ---------------- bucket-count histogram (196 bins, LDS-local) ----------------
__global__ __launch_bounds__(256) void k_hist(const int* __restrict__ dst,
                                              unsigned* __restrict__ bcnt, int E) {
  __shared__ unsigned h[256];
  const int t = threadIdx.x;
  h[t] = 0;
  __syncthreads();
  for (int i = blockIdx.x * 256 + t; i < E; i += gridDim.x * 256)
    atomicAdd(&h[(unsigned)dst[i] >> BSH], 1u);
  __syncthreads();
  if (h[t]) atomicAdd(&bcnt[t], h[t]);
}

// ------- exclusive scan of bucket counts -> bstart[nbk+1]; copy to bcur -------
__global__ __launch_bounds__(256) void k_scanB2(const unsigned* __restrict__ bcnt,
                                                unsigned* __restrict__ bstart,
                                                unsigned* __restrict__ bcur,
                                                int nbk, int E) {
  __shared__ unsigned sd[256];
  const int t = threadIdx.x;
  const unsigned v = (t < nbk) ? bcnt[t] : 0u;
  sd[t] = v;
  __syncthreads();
  for (int off = 1; off < 256; off <<= 1) {
    const unsigned u = (t >= off) ? sd[t - off] : 0u;
    __syncthreads();
    sd[t] += u;
    __syncthreads();
  }
  if (t < nbk) { const unsigned s = sd[t] - v; bstart[t] = s; bcur[t] = s; }
  if (t == 0) bstart[nbk] = (unsigned)E;
}

// ---- bucket pass: LDS counting-sort chunk by dst>>BSH, coalesced grouped write ----
__global__ __launch_bounds__(256) void k_bucket(const int* __restrict__ src,
                                                const int* __restrict__ dst,
                                                unsigned* __restrict__ bcur,
                                                uint32_t* __restrict__ pairs,
                                                int E, int nbk) {
  __shared__ uint32_t sorted[CH];
  __shared__ unsigned hist[256], starts[256], cur[256], gb[256];
  const int t = threadIdx.x;
  const int c0 = blockIdx.x * CH;

  hist[t] = 0;
  __syncthreads();

  uint32_t pk[16];
  unsigned bk[16];
#pragma unroll
  for (int k = 0; k < 16; ++k) {
    const int i = c0 + k * 256 + t;
    if (i < E) {
      const unsigned s = (unsigned)src[i], d = (unsigned)dst[i];
      bk[k] = d >> BSH;
      pk[k] = (s << BSH) | (d & BMSK);
      atomicAdd(&hist[bk[k]], 1u);
    } else bk[k] = 0xffffffffu;
  }
  __syncthreads();

  cur[t] = hist[t];
  __syncthreads();
  for (int off = 1; off < 256; off <<= 1) {
    const unsigned u = (t >= off) ? cur[t - off] : 0u;
    __syncthreads();
    cur[t] += u;
    __syncthreads();
  }
  starts[t] = cur[t] - hist[t];
  __syncthreads();
  cur[t] = starts[t];
  if (t < nbk && hist[t] > 0) gb[t] = atomicAdd(&bcur[t], hist[t]);
  __syncthreads();

#pragma unroll
  for (int k = 0; k < 16; ++k) {
    if (bk[k] != 0xffffffffu) {
      const unsigned p = atomicAdd(&cur[bk[k]], 1u);
      sorted[p] = pk[k];
    }
  }
  __syncthreads();

  const int cnt = (c0 + CH <= E) ? CH : (E - c0);
  for (int idx = t; idx < cnt; idx += 256) {
    int lo = 0, hi = nbk - 1;
    while (lo < hi) {
      const int mid = (lo + hi + 1) >> 1;
      if ((int)starts[mid] <= idx) lo = mid; else hi = mid - 1;
    }
    pairs[gb[lo] + (idx - starts[lo])] = sorted[idx];
  }
}

// ---- per-bucket: deg-hist + scan + rowptr/dinv + LDS-cursor scatter (no global atomics) ----
__global__ __launch_bounds__(256) void k_pernode(const uint32_t* __restrict__ pairs,
                                                 const unsigned* __restrict__ bstart,
                                                 int* __restrict__ rowptr,
                                                 float* __restrict__ dinv,
                                                 int* __restrict__ esrc,
                                                 int N, int E) {
  __shared__ unsigned hist[512];
  __shared__ unsigned sd[256];
  const int b = blockIdx.x;
  const int t = threadIdx.x;
  const unsigned beg = bstart[b], end = bstart[b + 1];

  hist[t] = 0; hist[t + 256] = 0;
  __syncthreads();
  for (unsigned i = beg + t; i < end; i += 256)
    atomicAdd(&hist[pairs[i] & BMSK], 1u);
  __syncthreads();

  const unsigned d0 = hist[2 * t], d1 = hist[2 * t + 1];
  const unsigned tt = d0 + d1;
  sd[t] = tt;
  __syncthreads();
  for (int off = 1; off < 256; off <<= 1) {
    const unsigned u = (t >= off) ? sd[t - off] : 0u;
    __syncthreads();
    sd[t] += u;
    __syncthreads();
  }
  const unsigned base = sd[t] - tt;
  const unsigned r0 = base, r1 = base + d0;
  hist[2 * t] = r0; hist[2 * t + 1] = r1;

  const int node0 = b << BSH;
  const unsigned dd[2] = {d0, d1};
  const unsigned rr[2] = {r0, r1};
#pragma unroll
  for (int k = 0; k < 2; ++k) {
    const int node = node0 + 2 * t + k;
    if (node < N) {
      rowptr[node] = (int)(beg + rr[k]);
      dinv[node] = rsqrtf((float)dd[k] + 1.0f);   // +1 = self loop
    }
  }
  if (b == 0 && t == 0) rowptr[N] = E;
  __syncthreads();

  for (unsigned i = beg + t; i < end; i += 256) {
    const uint32_t pk = pairs[i];
    const unsigned p = atomicAdd(&hist[pk & BMSK], 1u);
    esrc[beg + p] = (int)(pk >> BSH);
  }
}

// ---- gather: one wave per node, 8-deep MLP, atomic-free, fused epilogue ----
__global__ __launch_bounds__(256) void k_gather(const uint32_t* __restrict__ hB,
                                                const float* __restrict__ dinv,
                                                const int* __restrict__ rowptr,
                                                const int* __restrict__ esrc,
                                                const float* __restrict__ bias,
                                                float* __restrict__ out, int N) {
  const int lane = threadIdx.x & 63;
  const int v = (int)((blockIdx.x * blockDim.x + threadIdx.x) >> 6);
  if (v >= N) return;
  const uint32_t* hL = hB + lane;
  const uint32_t u = hL[(size_t)v << 6];
  float a0 = blo(u), a1 = bhi(u);                 // self term
  float b0 = 0.f, b1 = 0.f, c0 = 0.f, c1 = 0.f, e0 = 0.f, e1 = 0.f;
  const int beg = rowptr[v], end = rowptr[v + 1];
  for (int j0 = beg; j0 < end; j0 += 64) {
    const int cnt = min(64, end - j0);
    const int myS = (j0 + lane < end) ? esrc[j0 + lane] : 0;
    int k = 0;
    for (; k + 8 <= cnt; k += 8) {
      const int s0 = __shfl(myS, k),     s1 = __shfl(myS, k + 1);
      const int s2 = __shfl(myS, k + 2), s3 = __shfl(myS, k + 3);
      const int s4 = __shfl(myS, k + 4), s5 = __shfl(myS, k + 5);
      const int s6 = __shfl(myS, k + 6), s7 = __shfl(myS, k + 7);
      const uint32_t u0 = hL[(size_t)s0 << 6], u1 = hL[(size_t)s1 << 6];
      const uint32_t u2 = hL[(size_t)s2 << 6], u3 = hL[(size_t)s3 << 6];
      const uint32_t u4 = hL[(size_t)s4 << 6], u5 = hL[(size_t)s5 << 6];
      const uint32_t u6 = hL[(size_t)s6 << 6], u7 = hL[(size_t)s7 << 6];
      a0 += blo(u0); a1 += bhi(u0); b0 += blo(u1); b1 += bhi(u1);
      c0 += blo(u2); c1 += bhi(u2); e0 += blo(u3); e1 += bhi(u3);
      a0 += blo(u4); a1 += bhi(u4); b0 += blo(u5); b1 += bhi(u5);
      c0 += blo(u6); c1 += bhi(u6); e0 += blo(u7); e1 += bhi(u7);
    }
    for (; k < cnt; ++k) {
      const int s = __shfl(myS, k);
      const uint32_t us = hL[(size_t)s << 6];
      a0 += blo(us); a1 += bhi(us);
    }
  }
  a0 += b0 + c0 + e0;
  a1 += b1 + c1 + e1;
  const float dv = dinv[v];
  const int c = lane * 2;
  const float2 bv = *reinterpret_cast<const float2*>(&bias[c]);
  float2 r;
  r.x = fmaxf(fmaf(dv, a0, bv.x), 0.f);
  r.y = fmaxf(fmaf(dv, a1, bv.y), 0.f);
  *reinterpret_cast<float2*>(&out[(size_t)v * F + c]) = r;
}

extern "C" void kernel_launch(void* const* d_in, const int* in_sizes, int n_in,
                              void* d_out, int out_size, void* d_ws, size_t ws_size,
                              hipStream_t stream) {
  const float* x  = (const float*)d_in[0];
  const int*   ei = (const int*)d_in[1];
  const float* W  = (const float*)d_in[2];
  const float* b  = (const float*)d_in[3];
  float* out = (float*)d_out;

  const int N = in_sizes[0] / F;   // 100000
  const int E = in_sizes[1] / 2;   // 1600000
  const int* srcA = ei;
  const int* dstA = ei + E;

  const int NB = (N + (1 << BSH) - 1) >> BSH;   // 196 buckets
  const int NCH = (E + CH - 1) / CH;            // 391 chunks

  auto aln = [](size_t v) { return (v + 255) & ~(size_t)255; };
  char* base = (char*)d_ws;
  size_t off = 0;
  uint32_t* hB = (uint32_t*)(base + off);     off += aln((size_t)N * (F / 2) * sizeof(uint32_t));
  int* esrc = (int*)(base + off);             off += aln((size_t)E * sizeof(int));
  uint32_t* pairs = (uint32_t*)(base + off);  off += aln((size_t)E * sizeof(uint32_t));
  float* dinv = (float*)(base + off);         off += aln((size_t)N * sizeof(float));
  int* rowptr = (int*)(base + off);           off += aln((size_t)(N + 1) * sizeof(int));
  unsigned* bcnt = (unsigned*)(base + off);   off += aln(256 * sizeof(unsigned));
  unsigned* bstart = (unsigned*)(base + off); off += aln(257 * sizeof(unsigned));
  unsigned* bcur = (unsigned*)(base + off);   off += aln(256 * sizeof(unsigned));

  hipMemsetAsync(bcnt, 0, 256 * sizeof(unsigned), stream);
  k_hist<<<256, 256, 0, stream>>>(dstA, bcnt, E);
  k_scanB2<<<1, 256, 0, stream>>>(bcnt, bstart, bcur, NB, E);
  k_bucket<<<NCH, 256, 0, stream>>>(srcA, dstA, bcur, pairs, E, NB);
  k_pernode<<<NB, 256, 0, stream>>>(pairs, bstart, rowptr, dinv, esrc, N, E);
  k_gemm<<<(N + 63) / 64, 256, 0, stream>>>(x, W, dinv, hB, N);
  k_gather<<<(N * 64 + 255) / 256, 256, 0, stream>>>(hB, dinv, rowptr, esrc, b, out, N);
}

// Round 13
// 225.853 us; speedup vs baseline: 3.9990x; 1.0737x over previous
//
#include <hip/hip_runtime.h>

#define F 128
#define CH 4096   // edges per k_bucket block
#define BSH 9     // bucket = dst >> BSH (512 nodes/bucket)
#define BMSK ((1u << BSH) - 1u)
#define PCAP 9216 // pernode LDS pair-stage capacity (avg bucket = 8192, +11σ headroom)

typedef __bf16 bf16x8 __attribute__((ext_vector_type(8)));
typedef float f32x4 __attribute__((ext_vector_type(4)));

// round-to-nearest-even f32 -> bf16 bits
__device__ inline uint32_t bfbits(float f) {
  uint32_t x = __float_as_uint(f);
  return (x + 0x7fffu + ((x >> 16) & 1u)) >> 16;
}
__device__ inline float blo(uint32_t u) { return __uint_as_float(u << 16); }
__device__ inline float bhi(uint32_t u) { return __uint_as_float(u & 0xffff0000u); }

// ---------------- prepW: W (f32 [128][128]) -> frag-ready bf16 uint4[2048] ----------------
// layout: wf[(kc*8+nc)*64 + lane] = 8 bf16 B-frag (col = nc*16 + (l&15), k = kc*32+(l>>4)*8+i)
__global__ __launch_bounds__(256) void k_prepW(const float* __restrict__ W,
                                               uint4* __restrict__ wf) {
  const int s = blockIdx.x * 256 + threadIdx.x;   // 0..2047
  const int l = s & 63, nc = (s >> 6) & 7, kc = s >> 9;
  const int kbase = kc * 32 + ((l >> 4) << 3);
  const int col = nc * 16 + (l & 15);
  uint32_t q[4];
#pragma unroll
  for (int ii = 0; ii < 4; ++ii) {
    const uint32_t lo2 = bfbits(W[(size_t)(kbase + 2 * ii) * F + col]);
    const uint32_t hi2 = bfbits(W[(size_t)(kbase + 2 * ii + 1) * F + col]);
    q[ii] = lo2 | (hi2 << 16);
  }
  wf[s] = make_uint4(q[0], q[1], q[2], q[3]);
}

// ---------------- GEMM (MFMA bf16): h' = dinv[row] * (x @ W), stored bf16 ----------------
__global__ __launch_bounds__(256) void k_gemm(const float* __restrict__ x,
                                              const uint4* __restrict__ wf,
                                              const float* __restrict__ dinv,
                                              uint32_t* __restrict__ hB, int N) {
  __shared__ uint4 wb[2048];
  const int t = threadIdx.x;
#pragma unroll
  for (int p = 0; p < 8; ++p) wb[p * 256 + t] = wf[p * 256 + t];   // pure copy staging
  __syncthreads();

  const int w = t >> 6, l = t & 63;
  const int r0 = blockIdx.x * 64 + w * 16;
  const int arow = r0 + (l & 15);
  const int kb = (l >> 4) << 3;

  bf16x8 af[4];
#pragma unroll
  for (int kc = 0; kc < 4; ++kc) {
    float4 v0 = make_float4(0.f, 0.f, 0.f, 0.f), v1 = v0;
    if (arow < N) {
      v0 = *reinterpret_cast<const float4*>(&x[(size_t)arow * F + kc * 32 + kb]);
      v1 = *reinterpret_cast<const float4*>(&x[(size_t)arow * F + kc * 32 + kb + 4]);
    }
    const uint4 u = make_uint4(bfbits(v0.x) | (bfbits(v0.y) << 16),
                               bfbits(v0.z) | (bfbits(v0.w) << 16),
                               bfbits(v1.x) | (bfbits(v1.y) << 16),
                               bfbits(v1.z) | (bfbits(v1.w) << 16));
    af[kc] = __builtin_bit_cast(bf16x8, u);
  }

  f32x4 acc[8];
#pragma unroll
  for (int nc = 0; nc < 8; ++nc) acc[nc] = (f32x4){0.f, 0.f, 0.f, 0.f};

#pragma unroll
  for (int kc = 0; kc < 4; ++kc) {
#pragma unroll
    for (int nc = 0; nc < 8; ++nc) {
      const bf16x8 bf = __builtin_bit_cast(bf16x8, wb[(kc * 8 + nc) * 64 + l]);
      acc[nc] = __builtin_amdgcn_mfma_f32_16x16x32_bf16(af[kc], bf, acc[nc], 0, 0, 0);
    }
  }

  ushort* hBs = (ushort*)hB;
#pragma unroll
  for (int r = 0; r < 4; ++r) {
    const int row = r0 + ((l >> 4) << 2) + r;
    if (row < N) {
      const float dv = dinv[row];
#pragma unroll
      for (int nc = 0; nc < 8; ++nc)
        hBs[(size_t)row * F + nc * 16 + (l & 15)] = (ushort)bfbits(acc[nc][r] * dv);
    }
  }
}

// ---------------- bucket-count histogram (196 bins, LDS-local) ----------------
__global__ __launch_bounds__(256) void k_hist(const int* __restrict__ dst,
                                              unsigned* __restrict__ bcnt, int E) {
  __shared__ unsigned h[256];
  const int t = threadIdx.x;
  h[t] = 0;
  __syncthreads();
  for (int i = blockIdx.x * 256 + t; i < E; i += gridDim.x * 256)
    atomicAdd(&h[(unsigned)dst[i] >> BSH], 1u);
  __syncthreads();
  if (h[t]) atomicAdd(&bcnt[t], h[t]);
}

// ------- exclusive scan of bucket counts -> bstart[nbk+1]; copy to bcur -------
__global__ __launch_bounds__(256) void k_scanB2(const unsigned* __restrict__ bcnt,
                                                unsigned* __restrict__ bstart,
                                                unsigned* __restrict__ bcur,
                                                int nbk, int E) {
  __shared__ unsigned sd[256];
  const int t = threadIdx.x;
  const unsigned v = (t < nbk) ? bcnt[t] : 0u;
  sd[t] = v;
  __syncthreads();
  for (int off = 1; off < 256; off <<= 1) {
    const unsigned u = (t >= off) ? sd[t - off] : 0u;
    __syncthreads();
    sd[t] += u;
    __syncthreads();
  }
  if (t < nbk) { const unsigned s = sd[t] - v; bstart[t] = s; bcur[t] = s; }
  if (t == 0) bstart[nbk] = (unsigned)E;
}

// ---- bucket pass: LDS counting-sort chunk by dst>>BSH, coalesced grouped write ----
__global__ __launch_bounds__(256) void k_bucket(const int* __restrict__ src,
                                                const int* __restrict__ dst,
                                                unsigned* __restrict__ bcur,
                                                uint32_t* __restrict__ pairs,
                                                int E, int nbk) {
  __shared__ uint32_t sorted[CH];
  __shared__ unsigned char bkarr[CH];             // bucket id per sorted slot
  __shared__ unsigned hist[256], starts[256], cur[256], gb[256];
  const int t = threadIdx.x;
  const int c0 = blockIdx.x * CH;

  hist[t] = 0;
  __syncthreads();

  uint32_t pk[16];
  unsigned bk[16];
#pragma unroll
  for (int k = 0; k < 16; ++k) {
    const int i = c0 + k * 256 + t;
    if (i < E) {
      const unsigned s = (unsigned)src[i], d = (unsigned)dst[i];
      bk[k] = d >> BSH;
      pk[k] = (s << BSH) | (d & BMSK);
      atomicAdd(&hist[bk[k]], 1u);
    } else bk[k] = 0xffffffffu;
  }
  __syncthreads();

  cur[t] = hist[t];
  __syncthreads();
  for (int off = 1; off < 256; off <<= 1) {
    const unsigned u = (t >= off) ? cur[t - off] : 0u;
    __syncthreads();
    cur[t] += u;
    __syncthreads();
  }
  starts[t] = cur[t] - hist[t];
  __syncthreads();
  cur[t] = starts[t];
  if (t < nbk && hist[t] > 0) gb[t] = atomicAdd(&bcur[t], hist[t]);
  __syncthreads();

#pragma unroll
  for (int k = 0; k < 16; ++k) {
    if (bk[k] != 0xffffffffu) {
      const unsigned p = atomicAdd(&cur[bk[k]], 1u);
      sorted[p] = pk[k];
      bkarr[p] = (unsigned char)bk[k];
    }
  }
  __syncthreads();

  const int cnt = (c0 + CH <= E) ? CH : (E - c0);
  for (int idx = t; idx < cnt; idx += 256) {
    const int lo = (int)bkarr[idx];               // direct lookup, no binary search
    pairs[gb[lo] + (idx - starts[lo])] = sorted[idx];
  }
}

// ---- per-bucket: deg-hist + scan + rowptr/dinv + LDS-cursor scatter; pairs LDS-staged ----
__global__ __launch_bounds__(256) void k_pernode(const uint32_t* __restrict__ pairs,
                                                 const unsigned* __restrict__ bstart,
                                                 int* __restrict__ rowptr,
                                                 float* __restrict__ dinv,
                                                 int* __restrict__ esrc,
                                                 int N, int E) {
  __shared__ uint32_t pl[PCAP];
  __shared__ unsigned hist[512];
  __shared__ unsigned sd[256];
  const int b = blockIdx.x;
  const int t = threadIdx.x;
  const unsigned beg = bstart[b], end = bstart[b + 1];
  const int cnt = (int)(end - beg);
  const bool inL = (cnt <= PCAP);

  hist[t] = 0; hist[t + 256] = 0;
  if (inL) for (int i = t; i < cnt; i += 256) pl[i] = pairs[beg + i];
  __syncthreads();
  for (int i = t; i < cnt; i += 256) {
    const uint32_t pk = inL ? pl[i] : pairs[beg + i];
    atomicAdd(&hist[pk & BMSK], 1u);
  }
  __syncthreads();

  const unsigned d0 = hist[2 * t], d1 = hist[2 * t + 1];
  const unsigned tt = d0 + d1;
  sd[t] = tt;
  __syncthreads();
  for (int off = 1; off < 256; off <<= 1) {
    const unsigned u = (t >= off) ? sd[t - off] : 0u;
    __syncthreads();
    sd[t] += u;
    __syncthreads();
  }
  const unsigned base = sd[t] - tt;
  const unsigned r0 = base, r1 = base + d0;
  hist[2 * t] = r0; hist[2 * t + 1] = r1;

  const int node0 = b << BSH;
  const unsigned dd[2] = {d0, d1};
  const unsigned rr[2] = {r0, r1};
#pragma unroll
  for (int k = 0; k < 2; ++k) {
    const int node = node0 + 2 * t + k;
    if (node < N) {
      rowptr[node] = (int)(beg + rr[k]);
      dinv[node] = rsqrtf((float)dd[k] + 1.0f);   // +1 = self loop
    }
  }
  if (b == 0 && t == 0) rowptr[N] = E;
  __syncthreads();

  for (int i = t; i < cnt; i += 256) {
    const uint32_t pk = inL ? pl[i] : pairs[beg + i];
    const unsigned p = atomicAdd(&hist[pk & BMSK], 1u);
    esrc[beg + p] = (int)(pk >> BSH);
  }
}

// ---- gather: one wave per node, edge-pair processing (dwordx2), fused epilogue ----
// lanes split by edge parity: half=lane>>5 handles edges k+half; lane covers 4 cols.
__global__ __launch_bounds__(256) void k_gather(const uint32_t* __restrict__ hB,
                                                const float* __restrict__ dinv,
                                                const int* __restrict__ rowptr,
                                                const int* __restrict__ esrc,
                                                const float* __restrict__ bias,
                                                float* __restrict__ out, int N) {
  const int l = threadIdx.x & 63;
  const int half = l >> 5;
  const int lh = l & 31;
  const int v = (int)((blockIdx.x * blockDim.x + threadIdx.x) >> 6);
  if (v >= N) return;
  const uint2* hR = reinterpret_cast<const uint2*>(hB) + lh;   // row = s*32 uint2
  float a0 = 0.f, a1 = 0.f, a2 = 0.f, a3 = 0.f;
  float b0 = 0.f, b1 = 0.f, b2 = 0.f, b3 = 0.f;
  const int beg = rowptr[v], end = rowptr[v + 1];
  for (int j0 = beg; j0 < end; j0 += 64) {
    const int cnt = min(64, end - j0);
    const int myS = (j0 + l < end) ? esrc[j0 + l] : 0;
    int k = 0;
    for (; k + 8 <= cnt; k += 8) {
      const int sE0 = __shfl(myS, k),     sO0 = __shfl(myS, k + 1);
      const int sE1 = __shfl(myS, k + 2), sO1 = __shfl(myS, k + 3);
      const int sE2 = __shfl(myS, k + 4), sO2 = __shfl(myS, k + 5);
      const int sE3 = __shfl(myS, k + 6), sO3 = __shfl(myS, k + 7);
      const uint2 u0 = hR[(size_t)(half ? sO0 : sE0) << 5];
      const uint2 u1 = hR[(size_t)(half ? sO1 : sE1) << 5];
      const uint2 u2 = hR[(size_t)(half ? sO2 : sE2) << 5];
      const uint2 u3 = hR[(size_t)(half ? sO3 : sE3) << 5];
      a0 += blo(u0.x); a1 += bhi(u0.x); a2 += blo(u0.y); a3 += bhi(u0.y);
      b0 += blo(u1.x); b1 += bhi(u1.x); b2 += blo(u1.y); b3 += bhi(u1.y);
      a0 += blo(u2.x); a1 += bhi(u2.x); a2 += blo(u2.y); a3 += bhi(u2.y);
      b0 += blo(u3.x); b1 += bhi(u3.x); b2 += blo(u3.y); b3 += bhi(u3.y);
    }
    for (; k < cnt; k += 2) {
      const int idx = k + half;
      const int sE = __shfl(myS, k);
      const int sO = __shfl(myS, min(k + 1, cnt - 1));
      if (idx < cnt) {
        const uint2 u = hR[(size_t)(half ? sO : sE) << 5];
        a0 += blo(u.x); a1 += bhi(u.x); a2 += blo(u.y); a3 += bhi(u.y);
      }
    }
  }
  a0 += b0; a1 += b1; a2 += b2; a3 += b3;
  a0 += __shfl_xor(a0, 32);
  a1 += __shfl_xor(a1, 32);
  a2 += __shfl_xor(a2, 32);
  a3 += __shfl_xor(a3, 32);
  if (half == 0) {
    const uint2 us = hR[(size_t)v << 5];          // self term h'[v]
    a0 += blo(us.x); a1 += bhi(us.x); a2 += blo(us.y); a3 += bhi(us.y);
    const float dv = dinv[v];
    const float4 bv = *reinterpret_cast<const float4*>(&bias[lh * 4]);
    float4 r;
    r.x = fmaxf(fmaf(dv, a0, bv.x), 0.f);
    r.y = fmaxf(fmaf(dv, a1, bv.y), 0.f);
    r.z = fmaxf(fmaf(dv, a2, bv.z), 0.f);
    r.w = fmaxf(fmaf(dv, a3, bv.w), 0.f);
    *reinterpret_cast<float4*>(&out[(size_t)v * F + lh * 4]) = r;
  }
}

extern "C" void kernel_launch(void* const* d_in, const int* in_sizes, int n_in,
                              void* d_out, int out_size, void* d_ws, size_t ws_size,
                              hipStream_t stream) {
  const float* x  = (const float*)d_in[0];
  const int*   ei = (const int*)d_in[1];
  const float* W  = (const float*)d_in[2];
  const float* b  = (const float*)d_in[3];
  float* out = (float*)d_out;

  const int N = in_sizes[0] / F;   // 100000
  const int E = in_sizes[1] / 2;   // 1600000
  const int* srcA = ei;
  const int* dstA = ei + E;

  const int NB = (N + (1 << BSH) - 1) >> BSH;   // 196 buckets
  const int NCH = (E + CH - 1) / CH;            // 391 chunks

  auto aln = [](size_t v) { return (v + 255) & ~(size_t)255; };
  char* base = (char*)d_ws;
  size_t off = 0;
  uint32_t* hB = (uint32_t*)(base + off);     off += aln((size_t)N * (F / 2) * sizeof(uint32_t));
  int* esrc = (int*)(base + off);             off += aln((size_t)E * sizeof(int));
  uint32_t* pairs = (uint32_t*)(base + off);  off += aln((size_t)E * sizeof(uint32_t));
  float* dinv = (float*)(base + off);         off += aln((size_t)N * sizeof(float));
  int* rowptr = (int*)(base + off);           off += aln((size_t)(N + 1) * sizeof(int));
  unsigned* bcnt = (unsigned*)(base + off);   off += aln(256 * sizeof(unsigned));
  unsigned* bstart = (unsigned*)(base + off); off += aln(257 * sizeof(unsigned));
  unsigned* bcur = (unsigned*)(base + off);   off += aln(256 * sizeof(unsigned));
  uint4* wfrag = (uint4*)(base + off);        off += aln(2048 * sizeof(uint4));

  hipMemsetAsync(bcnt, 0, 256 * sizeof(unsigned), stream);
  k_prepW<<<8, 256, 0, stream>>>(W, wfrag);
  k_hist<<<256, 256, 0, stream>>>(dstA, bcnt, E);
  k_scanB2<<<1, 256, 0, stream>>>(bcnt, bstart, bcur, NB, E);
  k_bucket<<<NCH, 256, 0, stream>>>(srcA, dstA, bcur, pairs, E, NB);
  k_pernode<<<NB, 256, 0, stream>>>(pairs, bstart, rowptr, dinv, esrc, N, E);
  k_gemm<<<(N + 63) / 64, 256, 0, stream>>>(x, wfrag, dinv, hB, N);
  k_gather<<<(N * 64 + 255) / 256, 256, 0, stream>>>(hB, dinv, rowptr, esrc, b, out, N);
}